// Round 2
// baseline (1093.147 us; speedup 1.0000x reference)
//
#include <hip/hip_runtime.h>

#define NN 4096          // nodes
#define NFEAT 512
#define NHID 64
#define NHEADS 8
#define OUTD 512
#define LRALPHA 0.2f

// ---------------- workspace layout (bytes) ----------------
#define OFF_BITS  (size_t)0            // 4096*128 u32 = 2 MB
#define OFF_WH1   (size_t)(2*1024*1024)        // 8*4096*64 f32 = 8 MB
#define OFF_SRC1  (OFF_WH1 + (size_t)8*1024*1024)   // 32768 f32
#define OFF_DST1  (OFF_SRC1 + (size_t)131072)
#define OFF_X1    (OFF_DST1 + (size_t)131072)       // 4096*512 f32 = 8 MB
#define OFF_WH2   (OFF_X1 + (size_t)8*1024*1024)    // 8 MB
#define OFF_SRC2  (OFF_WH2 + (size_t)8*1024*1024)   // 16 KB
#define OFF_DST2  (OFF_SRC2 + (size_t)16384)
#define OFF_H2    (OFF_DST2 + (size_t)16384)        // 8 MB
#define OFF_L1O   (OFF_H2 + (size_t)8*1024*1024)    // 4096*1024 f32 = 16 MB

// ---------------- pack adjacency into bitmask ----------------
// bits[i][w] bit b  <=>  adj[i][w*32+b] > 0.  Row stride = 128 u32.
__global__ __launch_bounds__(256) void pack_bits_kernel(
    const int* __restrict__ adj, unsigned int* __restrict__ bits)
{
    int wid  = (blockIdx.x * 256 + threadIdx.x) >> 6;  // global wave id
    int lane = threadIdx.x & 63;
    int row  = wid >> 6;            // 64 waves per row (4096/64)
    int j0   = (wid & 63) << 6;
    int v    = adj[(long)row * NN + j0 + lane];
    unsigned long long m = __ballot(v > 0);
    if (lane == 0)  bits[row * 128 + (j0 >> 5)]     = (unsigned int)m;
    if (lane == 32) bits[row * 128 + (j0 >> 5) + 1] = (unsigned int)(m >> 32);
}

// ---------------- generic tiled fp32 GEMM ----------------
// C[M,N] = act(A[M,K] @ B[K,N] + bias).  64x64 tile, BK=16, 256 thr, 4x4 micro.
template<int DO_BIAS, int DO_RELU>
__global__ __launch_bounds__(256) void gemm_kernel(
    const float* __restrict__ A, const float* __restrict__ B,
    float* __restrict__ C, const float* __restrict__ bias,
    int M, int N, int K, long bStrideZ, long cStrideZ)
{
    __shared__ float As[16][68];   // [k][m], padded
    __shared__ float Bs[16][68];   // [k][n]
    const int t  = threadIdx.x;
    const int m0 = blockIdx.x * 64;
    const int n0 = blockIdx.y * 64;
    B += bStrideZ * blockIdx.z;
    C += cStrideZ * blockIdx.z;
    const int cg = t & 15, rg = t >> 4;          // phase-2: cols cg*4.., rows rg*4..
    const int am = t >> 2, ak = (t & 3) << 2;    // A tile load mapping
    const int bk = t >> 4, bn = (t & 15) << 2;   // B tile load mapping
    float acc[4][4] = {};
    for (int k0 = 0; k0 < K; k0 += 16) {
        float4 av = *(const float4*)(A + (long)(m0 + am) * K + k0 + ak);
        float4 bv = *(const float4*)(B + (long)(k0 + bk) * N + n0 + bn);
        __syncthreads();
        As[ak + 0][am] = av.x; As[ak + 1][am] = av.y;
        As[ak + 2][am] = av.z; As[ak + 3][am] = av.w;
        *(float4*)&Bs[bk][bn] = bv;
        __syncthreads();
        #pragma unroll
        for (int k = 0; k < 16; ++k) {
            float4 a = *(const float4*)&As[k][rg * 4];
            float4 b = *(const float4*)&Bs[k][cg * 4];
            float ar[4] = {a.x, a.y, a.z, a.w};
            float br[4] = {b.x, b.y, b.z, b.w};
            #pragma unroll
            for (int i = 0; i < 4; ++i)
                #pragma unroll
                for (int j = 0; j < 4; ++j)
                    acc[i][j] += ar[i] * br[j];
        }
    }
    #pragma unroll
    for (int i = 0; i < 4; ++i) {
        int row = m0 + rg * 4 + i;
        int col = n0 + cg * 4;
        float4 o; float* po = &o.x;
        #pragma unroll
        for (int j = 0; j < 4; ++j) {
            float v = acc[i][j];
            if (DO_BIAS) v += bias[col + j];
            if (DO_RELU) v = v > 0.f ? v : 0.f;
            po[j] = v;
        }
        *(float4*)(C + (long)row * N + col) = o;
    }
}

// ---------------- src/dst projections ----------------
__global__ __launch_bounds__(256) void srcdst_kernel(
    const float* __restrict__ Wh, const float* __restrict__ a,
    float* __restrict__ src, float* __restrict__ dst, int HN, int Nn, int O)
{
    int wid  = (blockIdx.x * 256 + threadIdx.x) >> 6;
    int lane = threadIdx.x & 63;
    if (wid >= HN) return;
    int h = wid / Nn;
    const float* row = Wh + (long)wid * O;
    const float* ah  = a + (long)h * 2 * O;
    float s = 0.f, d = 0.f;
    for (int o = lane; o < O; o += 64) {
        float v = row[o];
        s += v * ah[o];
        d += v * ah[O + o];
    }
    #pragma unroll
    for (int off = 32; off > 0; off >>= 1) {
        s += __shfl_xor(s, off);
        d += __shfl_xor(d, off);
    }
    if (lane == 0) { src[wid] = s; dst[wid] = d; }
}

// ---------------- fused masked-softmax attention + PV + ELU ----------------
// One block: 64 output rows x 64 output cols.  Exact max via monotone-lrelu
// pre-pass (no online rescale).  Single pass over j in 64-tiles.
__global__ __launch_bounds__(256) void attn_kernel(
    const float* __restrict__ Wh, int whLD, long whHeadStride_y, int whColOff_y,
    const float* __restrict__ src, const float* __restrict__ dst, int snOff_y,
    const unsigned int* __restrict__ bits,
    float* __restrict__ out, int outColOff_y)
{
    __shared__ float dstS[NN];          // 16 KB
    __shared__ float Ps[64][68];        // P[row][j]
    __shared__ float WhS[64][68];       // Wh[j][o]
    __shared__ float srcS[64], mS[64], denomS[64];

    const int t  = threadIdx.x;
    const int i0 = blockIdx.x * 64;
    const int y  = blockIdx.y;
    Wh  += whHeadStride_y * (long)y;
    const int co = whColOff_y * y;
    src += (long)snOff_y * y;
    dst += (long)snOff_y * y;

    #pragma unroll
    for (int i = 0; i < 4; ++i) {
        int idx = (t + i * 256) * 4;
        *(float4*)&dstS[idx] = *(const float4*)&dst[idx];
    }
    if (t < 64) srcS[t] = src[i0 + t];
    __syncthreads();

    const int r = t >> 2, q = t & 3;    // phase-1 mapping: row r, quarter q

    // ---- pre-pass: exact max of dst over valid j, per row ----
    {
        float md = -3.0e38f;
        const unsigned int* brow = bits + (long)(i0 + r) * 128 + q * 32;
        for (int w = 0; w < 32; ++w) {
            unsigned int b = brow[w];
            if (!b) continue;
            int base = q * 1024 + w * 32;
            while (b) {
                int bi = __ffs(b) - 1;
                b &= b - 1;
                float v = dstS[base + bi];
                md = v > md ? v : md;
            }
        }
        md = fmaxf(md, __shfl_xor(md, 1));
        md = fmaxf(md, __shfl_xor(md, 2));
        if (q == 0) {
            float m;
            if (md < -2.9e38f) m = -3.0e38f;       // empty row sentinel
            else {
                float e = srcS[r] + md;
                m = e > 0.f ? e : LRALPHA * e;      // lrelu monotone => exact max
            }
            mS[r] = m;
        }
    }
    __syncthreads();

    const int cg = t & 15, rg = t >> 4;  // phase-2 mapping
    float acc[4][4] = {};
    float denomPart = 0.f;
    const float src_r = srcS[r];
    const float m_r   = mS[r];
    const bool  empty = (m_r < -2.9e38f);

    for (int jt = 0; jt < 64; ++jt) {
        const int j0 = jt * 64;
        // prefetch Wh tile (global) + bits word before barrier
        float4 wv[4];
        const float* wrow = Wh + (long)(j0 + r) * whLD + co + q * 16;
        #pragma unroll
        for (int i = 0; i < 4; ++i) wv[i] = *(const float4*)(wrow + i * 4);
        unsigned int bword = bits[(long)(i0 + r) * 128 + (j0 >> 5) + (q >> 1)];

        __syncthreads();  // prev phase-2 done with Ps/WhS
        #pragma unroll
        for (int i = 0; i < 4; ++i) *(float4*)&WhS[r][q * 16 + i * 4] = wv[i];

        // phase 1: P[r][q*16 .. q*16+15]
        #pragma unroll
        for (int i4 = 0; i4 < 4; ++i4) {
            float4 p; float* pp = &p.x;
            #pragma unroll
            for (int ii = 0; ii < 4; ++ii) {
                int jl = q * 16 + i4 * 4 + ii;
                float e = src_r + dstS[j0 + jl];
                e = e > 0.f ? e : LRALPHA * e;
                bool valid = (bword >> (((q & 1) << 4) + i4 * 4 + ii)) & 1;
                float w = 0.f;
                if (empty) w = 1.f;
                else if (valid) w = __expf(e - m_r);
                pp[ii] = w;
                denomPart += w;
            }
            *(float4*)&Ps[r][q * 16 + i4 * 4] = p;
        }
        __syncthreads();

        // phase 2: acc[4r][4c] += P[rows][j] * WhS[j][cols]
        for (int j = 0; j < 64; j += 4) {
            float4 pr[4], wr[4];
            #pragma unroll
            for (int i = 0; i < 4; ++i) pr[i] = *(const float4*)&Ps[rg * 4 + i][j];
            #pragma unroll
            for (int jj = 0; jj < 4; ++jj) wr[jj] = *(const float4*)&WhS[j + jj][cg * 4];
            #pragma unroll
            for (int i = 0; i < 4; ++i) {
                const float pf[4] = {pr[i].x, pr[i].y, pr[i].z, pr[i].w};
                #pragma unroll
                for (int jj = 0; jj < 4; ++jj) {
                    acc[i][0] += pf[jj] * wr[jj].x;
                    acc[i][1] += pf[jj] * wr[jj].y;
                    acc[i][2] += pf[jj] * wr[jj].z;
                    acc[i][3] += pf[jj] * wr[jj].w;
                }
            }
        }
    }

    // denominator reduce across the 4 q-threads of each row
    denomPart += __shfl_xor(denomPart, 1);
    denomPart += __shfl_xor(denomPart, 2);
    if (q == 0) denomS[r] = denomPart;
    __syncthreads();

    // epilogue: divide + ELU + store
    #pragma unroll
    for (int i = 0; i < 4; ++i) {
        int row = rg * 4 + i;
        float inv = 1.f / denomS[row];
        float4 o; float* po = &o.x;
        #pragma unroll
        for (int c = 0; c < 4; ++c) {
            float v = acc[i][c] * inv;
            v = v > 0.f ? v : (__expf(v) - 1.f);   // ELU(alpha=1)
            po[c] = v;
        }
        *(float4*)(out + (long)(i0 + row) * OUTD + outColOff_y * y + cg * 4) = o;
    }
}

extern "C" void kernel_launch(void* const* d_in, const int* in_sizes, int n_in,
                              void* d_out, int out_size, void* d_ws, size_t ws_size,
                              hipStream_t stream) {
    const float* x   = (const float*)d_in[0];
    const int*   adj = (const int*)d_in[1];
    const float* W1  = (const float*)d_in[2];
    const float* a1  = (const float*)d_in[3];
    const float* Wo  = (const float*)d_in[4];
    const float* ao  = (const float*)d_in[5];
    const float* l1w = (const float*)d_in[6];
    const float* l1b = (const float*)d_in[7];
    const float* l2w = (const float*)d_in[8];
    const float* l2b = (const float*)d_in[9];
    float* out = (float*)d_out;

    char* ws = (char*)d_ws;
    unsigned int* bits = (unsigned int*)(ws + OFF_BITS);
    float* Wh1  = (float*)(ws + OFF_WH1);
    float* src1 = (float*)(ws + OFF_SRC1);
    float* dst1 = (float*)(ws + OFF_DST1);
    float* x1   = (float*)(ws + OFF_X1);
    float* Wh2  = (float*)(ws + OFF_WH2);
    float* src2 = (float*)(ws + OFF_SRC2);
    float* dst2 = (float*)(ws + OFF_DST2);
    float* h2   = (float*)(ws + OFF_H2);
    float* l1o  = (float*)(ws + OFF_L1O);

    // 1) adjacency bitmask
    pack_bits_kernel<<<65536, 256, 0, stream>>>(adj, bits);
    // 2) Wh1[h] = x @ W1[h]
    gemm_kernel<0,0><<<dim3(64,1,8), 256, 0, stream>>>(
        x, W1, Wh1, nullptr, NN, NHID, NFEAT, (long)NFEAT*NHID, (long)NN*NHID);
    // 3) src1/dst1
    srcdst_kernel<<<8192, 256, 0, stream>>>(Wh1, a1, src1, dst1, NHEADS*NN, NN, NHID);
    // 4) layer-1 attention (8 heads), ELU, concat into x1[n][h*64+o]
    attn_kernel<<<dim3(64, 8), 256, 0, stream>>>(
        Wh1, NHID, (long)NN*NHID, 0, src1, dst1, NN, bits, x1, 64);
    // 5) Wh2 = x1 @ Wo
    gemm_kernel<0,0><<<dim3(64,8,1), 256, 0, stream>>>(
        x1, Wo, Wh2, nullptr, NN, OUTD, NHEADS*NHID, 0, 0);
    // 6) src2/dst2
    srcdst_kernel<<<1024, 256, 0, stream>>>(Wh2, ao, src2, dst2, NN, NN, OUTD);
    // 7) layer-2 attention (8 col-splits of 64), ELU
    attn_kernel<<<dim3(64, 8), 256, 0, stream>>>(
        Wh2, OUTD, 0L, 64, src2, dst2, 0, bits, h2, 64);
    // 8) lin1 + ReLU
    gemm_kernel<1,1><<<dim3(64,16,1), 256, 0, stream>>>(
        h2, l1w, l1o, l1b, NN, 1024, OUTD, 0, 0);
    // 9) lin2 -> out
    gemm_kernel<1,0><<<dim3(64,8,1), 256, 0, stream>>>(
        l1o, l2w, out, l2b, NN, OUTD, 1024, 0, 0);
}

// Round 3
// 958.650 us; speedup vs baseline: 1.1403x; 1.1403x over previous
//
#include <hip/hip_runtime.h>

#define NN 4096          // nodes
#define NFEAT 512
#define NHID 64
#define NHEADS 8
#define OUTD 512
#define LRALPHA 0.2f
#define NSPLIT 4         // j-dimension splits for attention
#define JS (NN / NSPLIT) // 1024 js per split

// ---------------- workspace layout (bytes) ----------------
#define OFF_BITS (size_t)0          // 4096*128 u32 = 2 MB
#define OFF_WHA  (size_t)0x200000   // 8 MB: Wh1, later Wh2
#define OFF_SRC  (size_t)0xA00000   // 128 KB (8*4096 f32)
#define OFF_DST  (size_t)0xA20000   // 128 KB
#define OFF_MDM  (size_t)0xA40000   // 512 KB: m [S][8][4096]
#define OFF_MDD  (size_t)0xAC0000   // 512 KB: d [S][8][4096]
#define OFF_XH   (size_t)0xB40000   // 8 MB: x1, later h2
#define OFF_PART (size_t)0x1340000  // 32 MB: attn partials, later l1o (16MB)
// end = 0x3340000 = 51.25 MB

// ---------------- pack adjacency into bitmask ----------------
__global__ __launch_bounds__(256) void pack_bits_kernel(
    const int* __restrict__ adj, unsigned int* __restrict__ bits)
{
    int wid  = (blockIdx.x * 256 + threadIdx.x) >> 6;
    int lane = threadIdx.x & 63;
    int row  = wid >> 6;
    int j0   = (wid & 63) << 6;
    int v    = adj[(long)row * NN + j0 + lane];
    unsigned long long m = __ballot(v > 0);
    if (lane == 0)  bits[row * 128 + (j0 >> 5)]     = (unsigned int)m;
    if (lane == 32) bits[row * 128 + (j0 >> 5) + 1] = (unsigned int)(m >> 32);
}

// ---------------- generic tiled fp32 GEMM ----------------
template<int DO_BIAS, int DO_RELU>
__global__ __launch_bounds__(256) void gemm_kernel(
    const float* __restrict__ A, const float* __restrict__ B,
    float* __restrict__ C, const float* __restrict__ bias,
    int M, int N, int K, long bStrideZ, long cStrideZ)
{
    __shared__ float As[16][68];
    __shared__ float Bs[16][68];
    const int t  = threadIdx.x;
    const int m0 = blockIdx.x * 64;
    const int n0 = blockIdx.y * 64;
    B += bStrideZ * blockIdx.z;
    C += cStrideZ * blockIdx.z;
    const int cg = t & 15, rg = t >> 4;
    const int am = t >> 2, ak = (t & 3) << 2;
    const int bk = t >> 4, bn = (t & 15) << 2;
    float acc[4][4] = {};
    for (int k0 = 0; k0 < K; k0 += 16) {
        float4 av = *(const float4*)(A + (long)(m0 + am) * K + k0 + ak);
        float4 bv = *(const float4*)(B + (long)(k0 + bk) * N + n0 + bn);
        __syncthreads();
        As[ak + 0][am] = av.x; As[ak + 1][am] = av.y;
        As[ak + 2][am] = av.z; As[ak + 3][am] = av.w;
        *(float4*)&Bs[bk][bn] = bv;
        __syncthreads();
        #pragma unroll
        for (int k = 0; k < 16; ++k) {
            float4 a = *(const float4*)&As[k][rg * 4];
            float4 b = *(const float4*)&Bs[k][cg * 4];
            float ar[4] = {a.x, a.y, a.z, a.w};
            float br[4] = {b.x, b.y, b.z, b.w};
            #pragma unroll
            for (int i = 0; i < 4; ++i)
                #pragma unroll
                for (int j = 0; j < 4; ++j)
                    acc[i][j] += ar[i] * br[j];
        }
    }
    #pragma unroll
    for (int i = 0; i < 4; ++i) {
        int row = m0 + rg * 4 + i;
        int col = n0 + cg * 4;
        float4 o; float* po = &o.x;
        #pragma unroll
        for (int j = 0; j < 4; ++j) {
            float v = acc[i][j];
            if (DO_BIAS) v += bias[col + j];
            if (DO_RELU) v = v > 0.f ? v : 0.f;
            po[j] = v;
        }
        *(float4*)(C + (long)row * N + col) = o;
    }
}

// ---------------- src/dst projections ----------------
__global__ __launch_bounds__(256) void srcdst_kernel(
    const float* __restrict__ Wh, const float* __restrict__ a,
    float* __restrict__ src, float* __restrict__ dst, int HN, int Nn, int O)
{
    int wid  = (blockIdx.x * 256 + threadIdx.x) >> 6;
    int lane = threadIdx.x & 63;
    if (wid >= HN) return;
    int h = wid / Nn;
    const float* row = Wh + (long)wid * O;
    const float* ah  = a + (long)h * 2 * O;
    float s = 0.f, d = 0.f;
    for (int o = lane; o < O; o += 64) {
        float v = row[o];
        s += v * ah[o];
        d += v * ah[O + o];
    }
    #pragma unroll
    for (int off = 32; off > 0; off >>= 1) {
        s += __shfl_xor(s, off);
        d += __shfl_xor(d, off);
    }
    if (lane == 0) { src[wid] = s; dst[wid] = d; }
}

// ---------------- split-j masked-softmax attention partials ----------------
// Block: 64 rows x 64 cols x JS js (blockIdx.z = js split).  Emits
// unnormalized partial A = sum w*Wh, local max m_b, local denom d_b.
// Empty split: m_b = -2e38 flag, w = 1 uniform (combines to reference's
// uniform softmax iff ALL splits empty; else underflows to exact 0).
__global__ __launch_bounds__(256) void attn_kernel(
    const float* __restrict__ Wh, int whLD, long whHeadStride_y, int whColOff_y,
    const float* __restrict__ src, const float* __restrict__ dst, int snOff_y,
    const unsigned int* __restrict__ bits,
    float* __restrict__ partA, float* __restrict__ md_m, float* __restrict__ md_d)
{
    __shared__ float dstS[JS];          // 4 KB
    __shared__ float Ps[64][68];        // 17.4 KB
    __shared__ float WhS[64][68];       // 17.4 KB
    __shared__ float srcS[64], mS[64], denomS[64];

    const int t  = threadIdx.x;
    const int i0 = blockIdx.x * 64;
    const int y  = blockIdx.y;
    const int js = blockIdx.z;
    Wh  += whHeadStride_y * (long)y;
    const int co = whColOff_y * y;
    src += (long)snOff_y * y;
    dst += (long)snOff_y * y;

    *(float4*)&dstS[t * 4] = *(const float4*)&dst[js * JS + t * 4];
    if (t < 64) srcS[t] = src[i0 + t];
    __syncthreads();

    const int r = t >> 2, q = t & 3;

    // ---- pre-pass: exact local max of dst over valid j in this split ----
    {
        float md = -3.0e38f;
        const unsigned int* brow = bits + (long)(i0 + r) * 128 + js * 32 + q * 8;
        for (int w = 0; w < 8; ++w) {
            unsigned int b = brow[w];
            if (!b) continue;
            int base = q * 256 + w * 32;
            while (b) {
                int bi = __ffs(b) - 1;
                b &= b - 1;
                float v = dstS[base + bi];
                md = v > md ? v : md;
            }
        }
        md = fmaxf(md, __shfl_xor(md, 1));
        md = fmaxf(md, __shfl_xor(md, 2));
        if (q == 0) {
            float m;
            if (md < -2.9e38f) m = -2.0e38f;        // empty-split flag
            else {
                float e = srcS[r] + md;
                m = e > 0.f ? e : LRALPHA * e;      // lrelu monotone => exact max
            }
            mS[r] = m;
        }
    }
    __syncthreads();

    const int cg = t & 15, rg = t >> 4;
    float acc[4][4] = {};
    float denomPart = 0.f;
    const float src_r = srcS[r];
    const float m_r   = mS[r];
    const bool  empty = (m_r <= -1.9e38f);

    for (int jt = 0; jt < JS / 64; ++jt) {
        const int j0 = jt * 64;
        float4 wv[4];
        const float* wrow = Wh + (long)(js * JS + j0 + r) * whLD + co + q * 16;
        #pragma unroll
        for (int i = 0; i < 4; ++i) wv[i] = *(const float4*)(wrow + i * 4);
        unsigned int bword = bits[(long)(i0 + r) * 128 + js * 32 + jt * 2 + (q >> 1)];

        __syncthreads();
        #pragma unroll
        for (int i = 0; i < 4; ++i) *(float4*)&WhS[r][q * 16 + i * 4] = wv[i];

        // phase 1: P[r][q*16 .. q*16+15]
        #pragma unroll
        for (int i4 = 0; i4 < 4; ++i4) {
            float4 p; float* pp = &p.x;
            #pragma unroll
            for (int ii = 0; ii < 4; ++ii) {
                int jl = q * 16 + i4 * 4 + ii;
                float e = src_r + dstS[j0 + jl];
                e = e > 0.f ? e : LRALPHA * e;
                bool valid = (bword >> (((q & 1) << 4) + i4 * 4 + ii)) & 1;
                float w = 0.f;
                if (empty) w = 1.f;
                else if (valid) w = __expf(e - m_r);
                pp[ii] = w;
                denomPart += w;
            }
            *(float4*)&Ps[r][q * 16 + i4 * 4] = p;
        }
        __syncthreads();

        // phase 2: acc += P[rows][j] * WhS[j][cols]
        for (int j = 0; j < 64; j += 4) {
            float4 pr[4], wr[4];
            #pragma unroll
            for (int i = 0; i < 4; ++i) pr[i] = *(const float4*)&Ps[rg * 4 + i][j];
            #pragma unroll
            for (int jj = 0; jj < 4; ++jj) wr[jj] = *(const float4*)&WhS[j + jj][cg * 4];
            #pragma unroll
            for (int i = 0; i < 4; ++i) {
                const float pf[4] = {pr[i].x, pr[i].y, pr[i].z, pr[i].w};
                #pragma unroll
                for (int jj = 0; jj < 4; ++jj) {
                    acc[i][0] += pf[jj] * wr[jj].x;
                    acc[i][1] += pf[jj] * wr[jj].y;
                    acc[i][2] += pf[jj] * wr[jj].z;
                    acc[i][3] += pf[jj] * wr[jj].w;
                }
            }
        }
    }

    denomPart += __shfl_xor(denomPart, 1);
    denomPart += __shfl_xor(denomPart, 2);
    if (q == 0) denomS[r] = denomPart;
    __syncthreads();

    // write partials (no normalize, no activation)
    #pragma unroll
    for (int i = 0; i < 4; ++i) {
        int row = rg * 4 + i;
        float4 o = {acc[i][0], acc[i][1], acc[i][2], acc[i][3]};
        *(float4*)(partA + ((long)js * NN + i0 + row) * OUTD + co /*layer2: 0*/
                   + (whColOff_y ? 0 : y * 64)  /* see note below */
                   + cg * 4) = o;
    }
    if (t < 64) {
        md_m[((long)js * NHEADS + y) * NN + i0 + t] = mS[t];
        md_d[((long)js * NHEADS + y) * NN + i0 + t] = denomS[t];
    }
}

// ---------------- combine split partials + ELU ----------------
__global__ __launch_bounds__(256) void combine_kernel(
    const float* __restrict__ partA, const float* __restrict__ md_m,
    const float* __restrict__ md_d, float* __restrict__ outp)
{
    int idx4 = (blockIdx.x * 256 + threadIdx.x) * 4;
    int row  = idx4 >> 9;          // /512
    int col  = idx4 & 511;
    int slot = col >> 6;
    float m[NSPLIT], w[NSPLIT];
    float M = -3.4e38f;
    #pragma unroll
    for (int s = 0; s < NSPLIT; ++s) {
        m[s] = md_m[((long)s * NHEADS + slot) * NN + row];
        M = fmaxf(M, m[s]);
    }
    float den = 0.f;
    #pragma unroll
    for (int s = 0; s < NSPLIT; ++s) {
        w[s] = __expf(m[s] - M);
        den += w[s] * md_d[((long)s * NHEADS + slot) * NN + row];
    }
    float4 num = {0.f, 0.f, 0.f, 0.f};
    #pragma unroll
    for (int s = 0; s < NSPLIT; ++s) {
        float4 a = *(const float4*)&partA[((long)s * NN + row) * OUTD + col];
        num.x += w[s] * a.x; num.y += w[s] * a.y;
        num.z += w[s] * a.z; num.w += w[s] * a.w;
    }
    float inv = 1.f / den;
    float4 o; float* po = &o.x; const float* pn = &num.x;
    #pragma unroll
    for (int j = 0; j < 4; ++j) {
        float v = pn[j] * inv;
        po[j] = v > 0.f ? v : (__expf(v) - 1.f);   // ELU
    }
    *(float4*)(outp + (long)row * OUTD + col) = o;
}

extern "C" void kernel_launch(void* const* d_in, const int* in_sizes, int n_in,
                              void* d_out, int out_size, void* d_ws, size_t ws_size,
                              hipStream_t stream) {
    const float* x   = (const float*)d_in[0];
    const int*   adj = (const int*)d_in[1];
    const float* W1  = (const float*)d_in[2];
    const float* a1  = (const float*)d_in[3];
    const float* Wo  = (const float*)d_in[4];
    const float* ao  = (const float*)d_in[5];
    const float* l1w = (const float*)d_in[6];
    const float* l1b = (const float*)d_in[7];
    const float* l2w = (const float*)d_in[8];
    const float* l2b = (const float*)d_in[9];
    float* out = (float*)d_out;

    char* ws = (char*)d_ws;
    unsigned int* bits = (unsigned int*)(ws + OFF_BITS);
    float* WhA  = (float*)(ws + OFF_WHA);   // Wh1 then Wh2
    float* srcB = (float*)(ws + OFF_SRC);
    float* dstB = (float*)(ws + OFF_DST);
    float* mdm  = (float*)(ws + OFF_MDM);
    float* mdd  = (float*)(ws + OFF_MDD);
    float* xh   = (float*)(ws + OFF_XH);    // x1 then h2
    float* part = (float*)(ws + OFF_PART);  // attn partials then l1o

    // 1) adjacency bitmask
    pack_bits_kernel<<<65536, 256, 0, stream>>>(adj, bits);
    // 2) Wh1[h] = x @ W1[h]
    gemm_kernel<0,0><<<dim3(64,1,8), 256, 0, stream>>>(
        x, W1, WhA, nullptr, NN, NHID, NFEAT, (long)NFEAT*NHID, (long)NN*NHID);
    // 3) src1/dst1
    srcdst_kernel<<<8192, 256, 0, stream>>>(WhA, a1, srcB, dstB, NHEADS*NN, NN, NHID);
    // 4) layer-1 attention partials (8 heads x 4 splits)
    attn_kernel<<<dim3(64, 8, NSPLIT), 256, 0, stream>>>(
        WhA, NHID, (long)NN*NHID, 0, srcB, dstB, NN, bits, part, mdm, mdd);
    // 5) combine -> x1 (+ELU)
    combine_kernel<<<2048, 256, 0, stream>>>(part, mdm, mdd, xh);
    // 6) Wh2 = x1 @ Wo   (reuses WhA)
    gemm_kernel<0,0><<<dim3(64,8,1), 256, 0, stream>>>(
        xh, Wo, WhA, nullptr, NN, OUTD, NHEADS*NHID, 0, 0);
    // 7) src2/dst2
    srcdst_kernel<<<1024, 256, 0, stream>>>(WhA, ao, srcB, dstB, NN, NN, OUTD);
    // 8) layer-2 attention partials (8 col-splits x 4 splits)
    attn_kernel<<<dim3(64, 8, NSPLIT), 256, 0, stream>>>(
        WhA, OUTD, 0L, 64, srcB, dstB, 0, bits, part, mdm, mdd);
    // 9) combine -> h2 (+ELU)  (x1 dead, reuse xh)
    combine_kernel<<<2048, 256, 0, stream>>>(part, mdm, mdd, xh);
    // 10) lin1 + ReLU  (partials dead, l1o at part)
    gemm_kernel<1,1><<<dim3(64,16,1), 256, 0, stream>>>(
        xh, l1w, part, l1b, NN, 1024, OUTD, 0, 0);
    // 11) lin2 -> out
    gemm_kernel<1,0><<<dim3(64,8,1), 256, 0, stream>>>(
        part, l2w, out, l2b, NN, OUTD, 1024, 0, 0);
}

// Round 4
// 587.128 us; speedup vs baseline: 1.8619x; 1.6328x over previous
//
#include <hip/hip_runtime.h>

#define NN 4096
#define NFEAT 512
#define NHID 64
#define NHEADS 8
#define OUTD 512
#define LRALPHA 0.2f
#define NSPLIT 2
#define JS (NN / NSPLIT)     // 2048
#define JTILES (JS / 64)     // 32

typedef __attribute__((ext_vector_type(4))) float f32x4;
typedef __attribute__((ext_vector_type(8))) short short8;

// ---------------- workspace layout (bytes), total 44.75 MB ----------------
#define OFF_BITS (size_t)0x0        // 2 MB
#define OFF_WHA  (size_t)0x200000   // 8 MB fp32 Wh (layer1 then layer2)
#define OFF_SRC  (size_t)0xA00000   // 128 KB
#define OFF_DST  (size_t)0xA20000   // 128 KB
#define OFF_MDM  (size_t)0xA40000   // 256 KB [2][8][4096]
#define OFF_MDD  (size_t)0xA80000   // 256 KB
#define OFF_XH   (size_t)0xAC0000   // 8 MB (x1 then h2)
#define OFF_WHH  (size_t)0x12C0000  // 4 MB bf16-hi [y][c][j]
#define OFF_WHL  (size_t)0x16C0000  // 4 MB bf16-lo
#define OFF_PART (size_t)0x1AC0000  // 16 MB partials, later l1o

__device__ inline unsigned short f2bf(float x) {   // RTNE float->bf16
    unsigned u = __float_as_uint(x);
    return (unsigned short)((u + 0x7FFFu + ((u >> 16) & 1u)) >> 16);
}

// ---------------- pack adjacency into bitmask ----------------
__global__ __launch_bounds__(256) void pack_bits_kernel(
    const int* __restrict__ adj, unsigned int* __restrict__ bits)
{
    int wid  = (blockIdx.x * 256 + threadIdx.x) >> 6;
    int lane = threadIdx.x & 63;
    int row  = wid >> 6;
    int j0   = (wid & 63) << 6;
    int v    = adj[(long)row * NN + j0 + lane];
    unsigned long long m = __ballot(v > 0);
    if (lane == 0)  bits[row * 128 + (j0 >> 5)]     = (unsigned int)m;
    if (lane == 32) bits[row * 128 + (j0 >> 5) + 1] = (unsigned int)(m >> 32);
}

// ---------------- generic tiled fp32 GEMM (unchanged) ----------------
template<int DO_BIAS, int DO_RELU>
__global__ __launch_bounds__(256) void gemm_kernel(
    const float* __restrict__ A, const float* __restrict__ B,
    float* __restrict__ C, const float* __restrict__ bias,
    int M, int N, int K, long bStrideZ, long cStrideZ)
{
    __shared__ float As[16][68];
    __shared__ float Bs[16][68];
    const int t  = threadIdx.x;
    const int m0 = blockIdx.x * 64;
    const int n0 = blockIdx.y * 64;
    B += bStrideZ * blockIdx.z;
    C += cStrideZ * blockIdx.z;
    const int cg = t & 15, rg = t >> 4;
    const int am = t >> 2, ak = (t & 3) << 2;
    const int bk = t >> 4, bn = (t & 15) << 2;
    float acc[4][4] = {};
    for (int k0 = 0; k0 < K; k0 += 16) {
        float4 av = *(const float4*)(A + (long)(m0 + am) * K + k0 + ak);
        float4 bv = *(const float4*)(B + (long)(k0 + bk) * N + n0 + bn);
        __syncthreads();
        As[ak + 0][am] = av.x; As[ak + 1][am] = av.y;
        As[ak + 2][am] = av.z; As[ak + 3][am] = av.w;
        *(float4*)&Bs[bk][bn] = bv;
        __syncthreads();
        #pragma unroll
        for (int k = 0; k < 16; ++k) {
            float4 a = *(const float4*)&As[k][rg * 4];
            float4 b = *(const float4*)&Bs[k][cg * 4];
            float ar[4] = {a.x, a.y, a.z, a.w};
            float br[4] = {b.x, b.y, b.z, b.w};
            #pragma unroll
            for (int i = 0; i < 4; ++i)
                #pragma unroll
                for (int j = 0; j < 4; ++j)
                    acc[i][j] += ar[i] * br[j];
        }
    }
    #pragma unroll
    for (int i = 0; i < 4; ++i) {
        int row = m0 + rg * 4 + i;
        int col = n0 + cg * 4;
        float4 o; float* po = &o.x;
        #pragma unroll
        for (int j = 0; j < 4; ++j) {
            float v = acc[i][j];
            if (DO_BIAS) v += bias[col + j];
            if (DO_RELU) v = v > 0.f ? v : 0.f;
            po[j] = v;
        }
        *(float4*)(C + (long)row * N + col) = o;
    }
}

// ---------------- src/dst projections ----------------
__global__ __launch_bounds__(256) void srcdst_kernel(
    const float* __restrict__ Wh, const float* __restrict__ a,
    float* __restrict__ src, float* __restrict__ dst, int HN, int Nn, int O)
{
    int wid  = (blockIdx.x * 256 + threadIdx.x) >> 6;
    int lane = threadIdx.x & 63;
    if (wid >= HN) return;
    int h = wid / Nn;
    const float* row = Wh + (long)wid * O;
    const float* ah  = a + (long)h * 2 * O;
    float s = 0.f, d = 0.f;
    for (int o = lane; o < O; o += 64) {
        float v = row[o];
        s += v * ah[o];
        d += v * ah[O + o];
    }
    #pragma unroll
    for (int off = 32; off > 0; off >>= 1) {
        s += __shfl_xor(s, off);
        d += __shfl_xor(d, off);
    }
    if (lane == 0) { src[wid] = s; dst[wid] = d; }
}

// ---------------- transpose + bf16 hi/lo split: out[y][c 64][j 4096] ----------------
__global__ __launch_bounds__(256) void whsplit_kernel(
    const float* __restrict__ Wh, long yStride, int ldJ,
    unsigned short* __restrict__ outH, unsigned short* __restrict__ outL)
{
    __shared__ float tile[64][68];
    const int t = threadIdx.x;
    const int j0 = blockIdx.x * 64;
    const int y = blockIdx.y;
    #pragma unroll
    for (int p = 0; p < 4; ++p) {
        int j = p * 16 + (t >> 4);
        int c = (t & 15) * 4;
        *(float4*)&tile[j][c] =
            *(const float4*)&Wh[(long)(j0 + j) * ldJ + (long)y * yStride + c];
    }
    __syncthreads();
    const int c = t >> 2, jb = (t & 3) * 16;
    short8 H0, H1, L0, L1;
    #pragma unroll
    for (int e = 0; e < 8; ++e) {
        float v = tile[jb + e][c];
        unsigned short h = f2bf(v);
        H0[e] = (short)h;
        L0[e] = (short)f2bf(v - __uint_as_float((unsigned)h << 16));
    }
    #pragma unroll
    for (int e = 0; e < 8; ++e) {
        float v = tile[jb + 8 + e][c];
        unsigned short h = f2bf(v);
        H1[e] = (short)h;
        L1[e] = (short)f2bf(v - __uint_as_float((unsigned)h << 16));
    }
    long ob = (long)y * 262144 + (long)c * 4096 + j0 + jb;
    *(short8*)&outH[ob]     = H0;
    *(short8*)&outH[ob + 8] = H1;
    *(short8*)&outL[ob]     = L0;
    *(short8*)&outL[ob + 8] = L1;
}

// ---------------- MFMA split-j attention partials ----------------
// Block: 128 rows x 64 cols x JS js (z = split). 8 waves; wave w = rows 16w..16w+15.
// P computed in A-fragment registers (bf16 hi/lo); Wh bf16 hi/lo staged in
// double-buffered LDS with blk^(c&7) swizzle. bf16x3 MFMA into fp32 acc.
__global__ __launch_bounds__(512, 4) void attn_kernel(
    const unsigned short* __restrict__ whH, const unsigned short* __restrict__ whL,
    const float* __restrict__ src, const float* __restrict__ dst, int snOff_y,
    const unsigned int* __restrict__ bits,
    float* __restrict__ partA, float* __restrict__ md_m, float* __restrict__ md_d)
{
    __shared__ unsigned short BH[2][4096];   // 16 KB (64c x 64j bf16-hi, swizzled)
    __shared__ unsigned short BL[2][4096];   // 16 KB
    __shared__ float dstS[JS];               // 8 KB
    __shared__ float srcS[128], mS[128];

    const int t  = threadIdx.x;
    const int i0 = blockIdx.x * 128;
    const int y  = blockIdx.y;
    const int js = blockIdx.z;
    src += (long)snOff_y * y;
    dst += (long)snOff_y * y;

    // staging mapping: thread t stages 16B: col sc, j-block sb (swizzled dest)
    const int sc = t >> 3, sb = t & 7;
    const long gbase = (long)y * 262144 + (long)sc * 4096 + js * JS + sb * 8;
    const int sdst = sc * 64 + ((sb ^ (sc & 7)) << 3);

    short8 stH = *(const short8*)(whH + gbase);          // tile 0
    short8 stL = *(const short8*)(whL + gbase);

    *(float4*)&dstS[t * 4] = *(const float4*)&dst[js * JS + t * 4];
    if (t < 128) srcS[t] = src[i0 + t];
    __syncthreads();

    // ---- pre-pass: exact max over valid j in this split (4 thr/row) ----
    {
        const int r = t >> 2, q = t & 3;
        float md = -3.0e38f;
        const unsigned int* brow = bits + (long)(i0 + r) * 128 + js * (JS / 32) + q * 16;
        for (int wi = 0; wi < 16; ++wi) {
            unsigned int b = brow[wi];
            if (!b) continue;
            int base = q * 512 + wi * 32;
            while (b) {
                int bi = __ffs(b) - 1; b &= b - 1;
                float v = dstS[base + bi];
                md = v > md ? v : md;
            }
        }
        md = fmaxf(md, __shfl_xor(md, 1));
        md = fmaxf(md, __shfl_xor(md, 2));
        if (q == 0) {
            float m;
            if (md < -2.9e38f) m = -2.0e38f;              // empty-split flag
            else { float e = srcS[r] + md; m = e > 0.f ? e : LRALPHA * e; }
            mS[r] = m;
        }
    }
    *(short8*)&BH[0][sdst] = stH;                        // commit tile 0
    *(short8*)&BL[0][sdst] = stL;
    stH = *(const short8*)(whH + gbase + 64);            // issue tile 1
    stL = *(const short8*)(whL + gbase + 64);
    __syncthreads();

    const int w = t >> 6, l = t & 63;
    const int rA = 16 * w + (l & 15);                    // A-frag row (local)
    const int q8 = (l >> 4) * 8;                         // k offset within 32
    const float src_r = srcS[rA];
    const float m_r   = mS[rA];
    const bool  empty = (m_r <= -1.9e38f);
    const unsigned int* browp = bits + (long)(i0 + rA) * 128 + js * (JS / 32);

    f32x4 acc[4] = {};
    float dp = 0.f;

    for (int jt = 0; jt < JTILES; ++jt) {
        const int cur = jt & 1;
        if (jt + 1 < JTILES) {                           // commit staged tile jt+1
            *(short8*)&BH[cur ^ 1][sdst] = stH;
            *(short8*)&BL[cur ^ 1][sdst] = stL;
        }
        if (jt + 2 < JTILES) {                           // issue tile jt+2
            stH = *(const short8*)(whH + gbase + (jt + 2) * 64);
            stL = *(const short8*)(whL + gbase + (jt + 2) * 64);
        }
        // ---- P in A-fragment registers (16 values: 2 kt x 8 e) ----
        unsigned int bw0 = browp[jt * 2], bw1 = browp[jt * 2 + 1];
        short8 aH[2], aL[2];
        #pragma unroll
        for (int kt = 0; kt < 2; ++kt) {
            unsigned int bw = kt ? bw1 : bw0;
            float4 d0 = *(const float4*)&dstS[jt * 64 + kt * 32 + q8];
            float4 d1 = *(const float4*)&dstS[jt * 64 + kt * 32 + q8 + 4];
            float dv[8] = {d0.x, d0.y, d0.z, d0.w, d1.x, d1.y, d1.z, d1.w};
            #pragma unroll
            for (int e = 0; e < 8; ++e) {
                float v = src_r + dv[e];
                v = v > 0.f ? v : LRALPHA * v;
                float pe = __expf(v - m_r);
                bool valid = (bw >> (q8 + e)) & 1u;
                float p = empty ? 1.f : (valid ? pe : 0.f);
                dp += p;
                unsigned short h = f2bf(p);
                float hf = __uint_as_float((unsigned)h << 16);
                aH[kt][e] = (short)h;
                aL[kt][e] = (short)f2bf(p - hf);
            }
        }
        // ---- bf16x3 MFMA: 4 col-tiles x 2 k-steps ----
        #pragma unroll
        for (int kt = 0; kt < 2; ++kt) {
            #pragma unroll
            for (int ct = 0; ct < 4; ++ct) {
                const int c = ct * 16 + (l & 15);
                const int off = c * 64 + ((((kt * 4) + (l >> 4)) ^ (c & 7)) << 3);
                short8 bh = *(const short8*)&BH[cur][off];
                short8 bl = *(const short8*)&BL[cur][off];
                acc[ct] = __builtin_amdgcn_mfma_f32_16x16x32_bf16(aH[kt], bh, acc[ct], 0, 0, 0);
                acc[ct] = __builtin_amdgcn_mfma_f32_16x16x32_bf16(aH[kt], bl, acc[ct], 0, 0, 0);
                acc[ct] = __builtin_amdgcn_mfma_f32_16x16x32_bf16(aL[kt], bh, acc[ct], 0, 0, 0);
            }
        }
        __syncthreads();
    }

    // denom: reduce over the 4 lanes holding each row (l, l+16, l+32, l+48)
    dp += __shfl_xor(dp, 16);
    dp += __shfl_xor(dp, 32);

    // partial write: D layout col=l&15, row=(l>>4)*4+reg
    const int colb = y * 64 + (l & 15);
    #pragma unroll
    for (int ct = 0; ct < 4; ++ct) {
        #pragma unroll
        for (int g = 0; g < 4; ++g) {
            int row = 16 * w + (l >> 4) * 4 + g;
            partA[((long)js * NN + i0 + row) * OUTD + colb + ct * 16] = acc[ct][g];
        }
    }
    if (l < 16) {
        long mdoff = ((long)js * NHEADS + y) * NN + i0 + 16 * w + l;
        md_m[mdoff] = m_r;     // rA == 16w+l here
        md_d[mdoff] = dp;
    }
}

// ---------------- combine split partials + ELU ----------------
__global__ __launch_bounds__(256) void combine_kernel(
    const float* __restrict__ partA, const float* __restrict__ md_m,
    const float* __restrict__ md_d, float* __restrict__ outp)
{
    int idx4 = (blockIdx.x * 256 + threadIdx.x) * 4;
    int row  = idx4 >> 9;
    int col  = idx4 & 511;
    int slot = col >> 6;
    float m[NSPLIT], w[NSPLIT];
    float M = -3.4e38f;
    #pragma unroll
    for (int s = 0; s < NSPLIT; ++s) {
        m[s] = md_m[((long)s * NHEADS + slot) * NN + row];
        M = fmaxf(M, m[s]);
    }
    float den = 0.f;
    #pragma unroll
    for (int s = 0; s < NSPLIT; ++s) {
        w[s] = __expf(m[s] - M);
        den += w[s] * md_d[((long)s * NHEADS + slot) * NN + row];
    }
    float4 num = {0.f, 0.f, 0.f, 0.f};
    #pragma unroll
    for (int s = 0; s < NSPLIT; ++s) {
        float4 a = *(const float4*)&partA[((long)s * NN + row) * OUTD + col];
        num.x += w[s] * a.x; num.y += w[s] * a.y;
        num.z += w[s] * a.z; num.w += w[s] * a.w;
    }
    float inv = 1.f / den;
    float4 o; float* po = &o.x; const float* pn = &num.x;
    #pragma unroll
    for (int j = 0; j < 4; ++j) {
        float v = pn[j] * inv;
        po[j] = v > 0.f ? v : (__expf(v) - 1.f);
    }
    *(float4*)(outp + (long)row * OUTD + col) = o;
}

extern "C" void kernel_launch(void* const* d_in, const int* in_sizes, int n_in,
                              void* d_out, int out_size, void* d_ws, size_t ws_size,
                              hipStream_t stream) {
    const float* x   = (const float*)d_in[0];
    const int*   adj = (const int*)d_in[1];
    const float* W1  = (const float*)d_in[2];
    const float* a1  = (const float*)d_in[3];
    const float* Wo  = (const float*)d_in[4];
    const float* ao  = (const float*)d_in[5];
    const float* l1w = (const float*)d_in[6];
    const float* l1b = (const float*)d_in[7];
    const float* l2w = (const float*)d_in[8];
    const float* l2b = (const float*)d_in[9];
    float* out = (float*)d_out;

    char* ws = (char*)d_ws;
    unsigned int* bits = (unsigned int*)(ws + OFF_BITS);
    float* WhA  = (float*)(ws + OFF_WHA);
    float* srcB = (float*)(ws + OFF_SRC);
    float* dstB = (float*)(ws + OFF_DST);
    float* mdm  = (float*)(ws + OFF_MDM);
    float* mdd  = (float*)(ws + OFF_MDD);
    float* xh   = (float*)(ws + OFF_XH);
    unsigned short* whH = (unsigned short*)(ws + OFF_WHH);
    unsigned short* whL = (unsigned short*)(ws + OFF_WHL);
    float* part = (float*)(ws + OFF_PART);

    // 1) adjacency bitmask
    pack_bits_kernel<<<65536, 256, 0, stream>>>(adj, bits);
    // 2) Wh1[h] = x @ W1[h]  -> WhA [8][4096][64]
    gemm_kernel<0,0><<<dim3(64,1,8), 256, 0, stream>>>(
        x, W1, WhA, nullptr, NN, NHID, NFEAT, (long)NFEAT*NHID, (long)NN*NHID);
    // 3) src1/dst1
    srcdst_kernel<<<8192, 256, 0, stream>>>(WhA, a1, srcB, dstB, NHEADS*NN, NN, NHID);
    // 4) transpose+split Wh1 -> whH/whL [y][c][j]
    whsplit_kernel<<<dim3(64, 8), 256, 0, stream>>>(WhA, (long)NN*NHID, NHID, whH, whL);
    // 5) layer-1 attention partials
    attn_kernel<<<dim3(32, 8, NSPLIT), 512, 0, stream>>>(
        whH, whL, srcB, dstB, NN, bits, part, mdm, mdd);
    // 6) combine -> x1
    combine_kernel<<<2048, 256, 0, stream>>>(part, mdm, mdd, xh);
    // 7) Wh2 = x1 @ Wo -> WhA [4096][512]
    gemm_kernel<0,0><<<dim3(64,8,1), 256, 0, stream>>>(
        xh, Wo, WhA, nullptr, NN, OUTD, NHEADS*NHID, 0, 0);
    // 8) src2/dst2
    srcdst_kernel<<<1024, 256, 0, stream>>>(WhA, ao, srcB, dstB, NN, NN, OUTD);
    // 9) transpose+split Wh2 (y = col-slice)
    whsplit_kernel<<<dim3(64, 8), 256, 0, stream>>>(WhA, 64L, OUTD, whH, whL);
    // 10) layer-2 attention partials
    attn_kernel<<<dim3(32, 8, NSPLIT), 512, 0, stream>>>(
        whH, whL, srcB, dstB, 0, bits, part, mdm, mdd);
    // 11) combine -> h2
    combine_kernel<<<2048, 256, 0, stream>>>(part, mdm, mdd, xh);
    // 12) lin1 + ReLU -> part (l1o)
    gemm_kernel<1,1><<<dim3(64,16,1), 256, 0, stream>>>(
        xh, l1w, part, l1b, NN, 1024, OUTD, 0, 0);
    // 13) lin2 -> out
    gemm_kernel<1,0><<<dim3(64,8,1), 256, 0, stream>>>(
        part, l2w, out, l2b, NN, OUTD, 1024, 0, 0);
}

// Round 5
// 462.542 us; speedup vs baseline: 2.3633x; 1.2693x over previous
//
#include <hip/hip_runtime.h>

#define NN 4096
#define NFEAT 512
#define NHID 64
#define NHEADS 8
#define OUTD 512
#define LRALPHA 0.2f
#define NSPLIT 2
#define JS (NN / NSPLIT)     // 2048
#define JTILES (JS / 64)     // 32

typedef __attribute__((ext_vector_type(4))) float f32x4;
typedef __attribute__((ext_vector_type(8))) short short8;
typedef __attribute__((ext_vector_type(4))) int   int4v;
typedef __attribute__((ext_vector_type(2))) unsigned uint2v;

// ---------------- workspace layout (bytes), total 48.75 MB ----------------
#define OFF_BITS (size_t)0x0        // 2 MB bitmask
#define OFF_WHA  (size_t)0x200000   // 8 MB fp32 Wh (layer1 [8][4096][64] / layer2 [4096][512])
#define OFF_SRC  (size_t)0xA00000   // 128 KB
#define OFF_DST  (size_t)0xA20000   // 128 KB
#define OFF_MDM  (size_t)0xA40000   // 256 KB [2][8][4096]
#define OFF_MDD  (size_t)0xA80000   // 256 KB
#define OFF_XHH  (size_t)0xAC0000   // 4 MB bf16 hi: x, then x1, then h2 [4096][512]
#define OFF_XHL  (size_t)0xEC0000   // 4 MB bf16 lo
#define OFF_WHH  (size_t)0x12C0000  // 4 MB attn-transposed Wh hi [y][c][j]
#define OFF_WHL  (size_t)0x16C0000  // 4 MB
#define OFF_PART (size_t)0x1AC0000  // 16 MB attn partials; then l1o hi/lo
#define OFF_L1OH OFF_PART           // 8 MB bf16 hi [4096][1024]
#define OFF_L1OL (OFF_PART + (size_t)0x800000)
#define OFF_W1TH (size_t)0x2AC0000  // [8][64][512] bf16 512 KB
#define OFF_W1TL (size_t)0x2B40000
#define OFF_WOTH (size_t)0x2BC0000  // [512][512]
#define OFF_WOTL (size_t)0x2C40000
#define OFF_L1WH (size_t)0x2CC0000  // [1024][512] 1 MB
#define OFF_L1WL (size_t)0x2DC0000
#define OFF_L2WH (size_t)0x2EC0000  // [512][1024] 1 MB
#define OFF_L2WL (size_t)0x2FC0000
// end 0x30C0000 = 48.75 MB

__device__ inline unsigned short f2bf(float x) {   // RTNE float->bf16
    unsigned u = __float_as_uint(x);
    return (unsigned short)((u + 0x7FFFu + ((u >> 16) & 1u)) >> 16);
}

// truncate-split pack: two fp32 -> one u32 of 2 bf16 (hi) and residual (lo)
#define PACK_PAIR(ve, vo, hw_, lw_) {                                   \
    unsigned ue = __float_as_uint(ve), uo = __float_as_uint(vo);        \
    unsigned ho = uo & 0xFFFF0000u;                                     \
    hw_ = (int)(ho | (ue >> 16));                                       \
    float le_ = (ve) - __uint_as_float(ue & 0xFFFF0000u);               \
    float lo_ = (vo) - __uint_as_float(ho);                             \
    lw_ = (int)((__float_as_uint(lo_) & 0xFFFF0000u) |                  \
                (__float_as_uint(le_) >> 16)); }

// ---------------- pack adjacency into bitmask ----------------
__global__ __launch_bounds__(256) void pack_bits_kernel(
    const int* __restrict__ adj, unsigned int* __restrict__ bits)
{
    int wid  = (blockIdx.x * 256 + threadIdx.x) >> 6;
    int lane = threadIdx.x & 63;
    int row  = wid >> 6;
    int j0   = (wid & 63) << 6;
    int v    = adj[(long)row * NN + j0 + lane];
    unsigned long long m = __ballot(v > 0);
    if (lane == 0)  bits[row * 128 + (j0 >> 5)]     = (unsigned int)m;
    if (lane == 32) bits[row * 128 + (j0 >> 5) + 1] = (unsigned int)(m >> 32);
}

// ---------------- split fp32 stream -> bf16 hi/lo (same layout) ----------------
__global__ __launch_bounds__(256) void splitA_kernel(
    const float* __restrict__ in, unsigned short* __restrict__ oh,
    unsigned short* __restrict__ ol)
{
    long i = ((long)blockIdx.x * 256 + threadIdx.x) * 8;
    float4 a = *(const float4*)&in[i], b = *(const float4*)&in[i + 4];
    float v[8] = {a.x, a.y, a.z, a.w, b.x, b.y, b.z, b.w};
    int4v hw, lw;
    #pragma unroll
    for (int pp = 0; pp < 4; ++pp) PACK_PAIR(v[2*pp], v[2*pp+1], hw[pp], lw[pp]);
    *(short8*)&oh[i] = __builtin_bit_cast(short8, hw);
    *(short8*)&ol[i] = __builtin_bit_cast(short8, lw);
}

// ---------------- transpose+split weights: fp32 [K][N] -> bf16 hi/lo [N][K] ----------------
__global__ __launch_bounds__(256) void splitBT_kernel(
    const float* __restrict__ B, unsigned short* __restrict__ oh,
    unsigned short* __restrict__ ol, int K, int N, long srcZ, long dstZ)
{
    __shared__ float tile[64][65];
    const int t = threadIdx.x;
    const int n0 = blockIdx.x * 64, k0 = blockIdx.y * 64;
    B  += srcZ * blockIdx.z;
    oh += dstZ * blockIdx.z;
    ol += dstZ * blockIdx.z;
    #pragma unroll
    for (int it = 0; it < 4; ++it) {
        int k = it * 16 + (t >> 4);
        *(float4*)&tile[k][(t & 15) * 4] =
            *(const float4*)&B[(long)(k0 + k) * N + n0 + (t & 15) * 4];
    }
    __syncthreads();
    const int n = t >> 2, kc = (t & 3) * 16;
    #pragma unroll
    for (int g = 0; g < 2; ++g) {
        int4v hw, lw;
        #pragma unroll
        for (int pp = 0; pp < 4; ++pp) {
            float ve = tile[kc + g * 8 + 2 * pp][n];
            float vo = tile[kc + g * 8 + 2 * pp + 1][n];
            PACK_PAIR(ve, vo, hw[pp], lw[pp]);
        }
        long ob = (long)(n0 + n) * K + k0 + kc + g * 8;
        *(short8*)&oh[ob] = __builtin_bit_cast(short8, hw);
        *(short8*)&ol[ob] = __builtin_bit_cast(short8, lw);
    }
}

// ---------------- bf16x3 MFMA GEMM ----------------
// C[M,N] = act(A@B + bias).  A: bf16 hi/lo [M][K] row-major; B: bf16 hi/lo
// [N][K] (pre-transposed).  Block 256thr/4 waves, tile 128x64, BK=32, dbuf LDS
// with kb^((row>>1)&3) swizzle (2-way max conflicts).  Wave w: rows w*32..+31.
template<int WF32, int WSPL, int DO_BIAS, int DO_RELU>
__global__ __launch_bounds__(256, 3) void mgemm_kernel(
    const unsigned short* __restrict__ Ah, const unsigned short* __restrict__ Al,
    const unsigned short* __restrict__ Bh, const unsigned short* __restrict__ Bl,
    float* __restrict__ C, unsigned short* __restrict__ Ch,
    unsigned short* __restrict__ Cl, const float* __restrict__ bias,
    int N, int K, long bZ, long cZ)
{
    __shared__ unsigned short AH[2][4096], AL[2][4096];   // 128x32
    __shared__ unsigned short BH[2][2048], BL[2][2048];   // 64x32

    const int t = threadIdx.x;
    const int m0 = blockIdx.x * 128, n0 = blockIdx.y * 64;
    Bh += bZ * blockIdx.z; Bl += bZ * blockIdx.z;
    if (WF32) C += cZ * blockIdx.z;

    // staging addresses (thread t stages A rows {t>>2, 64+(t>>2)}, B row t>>2)
    const int ar0 = t >> 2, ar1 = 64 + (t >> 2), akb = t & 3;
    const unsigned short* pAh = Ah + (long)(m0 + ar0) * K + akb * 8;
    const unsigned short* pAl = Al + (long)(m0 + ar0) * K + akb * 8;
    const unsigned short* pBh = Bh + (long)(n0 + ar0) * K + akb * 8;
    const unsigned short* pBl = Bl + (long)(n0 + ar0) * K + akb * 8;
    const long aRow1 = (long)64 * K;
    const int adst0 = ar0 * 32 + ((akb ^ ((ar0 >> 1) & 3)) << 3);
    const int adst1 = ar1 * 32 + ((akb ^ ((ar1 >> 1) & 3)) << 3);
    const int bdst  = adst0;

    short8 sh0, sh1, sl0, sl1, sbh, sbl;
    const int S = K / 32;

#define MG_LOAD(s) { long o = (long)(s) * 32;                     \
        sh0 = *(const short8*)(pAh + o);                          \
        sh1 = *(const short8*)(pAh + aRow1 + o);                  \
        sl0 = *(const short8*)(pAl + o);                          \
        sl1 = *(const short8*)(pAl + aRow1 + o);                  \
        sbh = *(const short8*)(pBh + o);                          \
        sbl = *(const short8*)(pBl + o); }
#define MG_COMMIT(b) {                                            \
        *(short8*)&AH[b][adst0] = sh0; *(short8*)&AH[b][adst1] = sh1; \
        *(short8*)&AL[b][adst0] = sl0; *(short8*)&AL[b][adst1] = sl1; \
        *(short8*)&BH[b][bdst]  = sbh; *(short8*)&BL[b][bdst]  = sbl; }

    MG_LOAD(0);
    MG_COMMIT(0);
    if (S > 1) MG_LOAD(1);
    __syncthreads();

    const int w = t >> 6, l = t & 63;
    const int kb = l >> 4;
    const int r0 = w * 32 + (l & 15), r1 = r0 + 16;
    const int ao0 = r0 * 32 + ((kb ^ ((r0 >> 1) & 3)) << 3);
    const int ao1 = r1 * 32 + ((kb ^ ((r1 >> 1) & 3)) << 3);

    f32x4 acc0[4] = {}, acc1[4] = {};

    for (int s = 0; s < S; ++s) {
        const int cur = s & 1;
        if (s + 1 < S) MG_COMMIT(cur ^ 1);
        if (s + 2 < S) MG_LOAD(s + 2);

        short8 a0h = *(const short8*)&AH[cur][ao0];
        short8 a0l = *(const short8*)&AL[cur][ao0];
        short8 a1h = *(const short8*)&AH[cur][ao1];
        short8 a1l = *(const short8*)&AL[cur][ao1];
        #pragma unroll
        for (int ct = 0; ct < 4; ++ct) {
            const int n = ct * 16 + (l & 15);
            const int bo = n * 32 + ((kb ^ ((n >> 1) & 3)) << 3);
            short8 bh = *(const short8*)&BH[cur][bo];
            short8 bl = *(const short8*)&BL[cur][bo];
            acc0[ct] = __builtin_amdgcn_mfma_f32_16x16x32_bf16(a0h, bh, acc0[ct], 0, 0, 0);
            acc0[ct] = __builtin_amdgcn_mfma_f32_16x16x32_bf16(a0h, bl, acc0[ct], 0, 0, 0);
            acc0[ct] = __builtin_amdgcn_mfma_f32_16x16x32_bf16(a0l, bh, acc0[ct], 0, 0, 0);
            acc1[ct] = __builtin_amdgcn_mfma_f32_16x16x32_bf16(a1h, bh, acc1[ct], 0, 0, 0);
            acc1[ct] = __builtin_amdgcn_mfma_f32_16x16x32_bf16(a1h, bl, acc1[ct], 0, 0, 0);
            acc1[ct] = __builtin_amdgcn_mfma_f32_16x16x32_bf16(a1l, bh, acc1[ct], 0, 0, 0);
        }
        __syncthreads();
    }
#undef MG_LOAD
#undef MG_COMMIT

    // epilogue: D layout col=l&15, row=(l>>4)*4+g
    #pragma unroll
    for (int rs = 0; rs < 2; ++rs) {
        #pragma unroll
        for (int ct = 0; ct < 4; ++ct) {
            const int col = n0 + ct * 16 + (l & 15);
            float b = DO_BIAS ? bias[col] : 0.f;
            f32x4 av = rs ? acc1[ct] : acc0[ct];
            #pragma unroll
            for (int g = 0; g < 4; ++g) {
                int row = m0 + w * 32 + rs * 16 + (l >> 4) * 4 + g;
                float v = av[g] + b;
                if (DO_RELU) v = v > 0.f ? v : 0.f;
                if (WF32) C[(long)row * N + col] = v;
                if (WSPL) {
                    unsigned u = __float_as_uint(v);
                    Ch[(long)row * N + col] = (unsigned short)(u >> 16);
                    float lo = v - __uint_as_float(u & 0xFFFF0000u);
                    Cl[(long)row * N + col] = (unsigned short)(__float_as_uint(lo) >> 16);
                }
            }
        }
    }
}

// ---------------- src/dst projections ----------------
__global__ __launch_bounds__(256) void srcdst_kernel(
    const float* __restrict__ Wh, const float* __restrict__ a,
    float* __restrict__ src, float* __restrict__ dst, int HN, int Nn, int O)
{
    int wid  = (blockIdx.x * 256 + threadIdx.x) >> 6;
    int lane = threadIdx.x & 63;
    if (wid >= HN) return;
    int h = wid / Nn;
    const float* row = Wh + (long)wid * O;
    const float* ah  = a + (long)h * 2 * O;
    float s = 0.f, d = 0.f;
    for (int o = lane; o < O; o += 64) {
        float v = row[o];
        s += v * ah[o];
        d += v * ah[O + o];
    }
    #pragma unroll
    for (int off = 32; off > 0; off >>= 1) {
        s += __shfl_xor(s, off);
        d += __shfl_xor(d, off);
    }
    if (lane == 0) { src[wid] = s; dst[wid] = d; }
}

// ---------------- transpose + bf16 hi/lo split: out[y][c 64][j 4096] ----------------
__global__ __launch_bounds__(256) void whsplit_kernel(
    const float* __restrict__ Wh, long yStride, int ldJ,
    unsigned short* __restrict__ outH, unsigned short* __restrict__ outL)
{
    __shared__ float tile[64][68];
    const int t = threadIdx.x;
    const int j0 = blockIdx.x * 64;
    const int y = blockIdx.y;
    #pragma unroll
    for (int p = 0; p < 4; ++p) {
        int j = p * 16 + (t >> 4);
        int c = (t & 15) * 4;
        *(float4*)&tile[j][c] =
            *(const float4*)&Wh[(long)(j0 + j) * ldJ + (long)y * yStride + c];
    }
    __syncthreads();
    const int c = t >> 2, jb = (t & 3) * 16;
    short8 H0, H1, L0, L1;
    #pragma unroll
    for (int e = 0; e < 8; ++e) {
        float v = tile[jb + e][c];
        unsigned short h = f2bf(v);
        H0[e] = (short)h;
        L0[e] = (short)f2bf(v - __uint_as_float((unsigned)h << 16));
    }
    #pragma unroll
    for (int e = 0; e < 8; ++e) {
        float v = tile[jb + 8 + e][c];
        unsigned short h = f2bf(v);
        H1[e] = (short)h;
        L1[e] = (short)f2bf(v - __uint_as_float((unsigned)h << 16));
    }
    long ob = (long)y * 262144 + (long)c * 4096 + j0 + jb;
    *(short8*)&outH[ob]     = H0;
    *(short8*)&outH[ob + 8] = H1;
    *(short8*)&outL[ob]     = L0;
    *(short8*)&outL[ob + 8] = L1;
}

// ---------------- MFMA split-j attention partials ----------------
__global__ __launch_bounds__(512, 4) void attn_kernel(
    const unsigned short* __restrict__ whH, const unsigned short* __restrict__ whL,
    const float* __restrict__ src, const float* __restrict__ dst, int snOff_y,
    const unsigned int* __restrict__ bits,
    float* __restrict__ partA, float* __restrict__ md_m, float* __restrict__ md_d)
{
    __shared__ unsigned short BH[2][4096];   // 64c x 64j bf16-hi, swizzled
    __shared__ unsigned short BL[2][4096];
    __shared__ float dstS[JS];
    __shared__ float srcS[128], mS[128];

    const int t  = threadIdx.x;
    const int i0 = blockIdx.x * 128;
    const int y  = blockIdx.y;
    const int js = blockIdx.z;
    src += (long)snOff_y * y;
    dst += (long)snOff_y * y;

    const int sc = t >> 3, sb = t & 7;
    const long gbase = (long)y * 262144 + (long)sc * 4096 + js * JS + sb * 8;
    const int sdst = sc * 64 + ((sb ^ (sc & 7)) << 3);

    short8 stH = *(const short8*)(whH + gbase);
    short8 stL = *(const short8*)(whL + gbase);

    *(float4*)&dstS[t * 4] = *(const float4*)&dst[js * JS + t * 4];
    if (t < 128) srcS[t] = src[i0 + t];
    __syncthreads();

    // ---- pre-pass: exact max over valid j in this split (4 thr/row) ----
    {
        const int r = t >> 2, q = t & 3;
        float md = -3.0e38f;
        const unsigned int* brow = bits + (long)(i0 + r) * 128 + js * (JS / 32) + q * 16;
        for (int wi = 0; wi < 16; ++wi) {
            unsigned int b = brow[wi];
            if (!b) continue;
            int base = q * 512 + wi * 32;
            while (b) {
                int bi = __ffs(b) - 1; b &= b - 1;
                float v = dstS[base + bi];
                md = v > md ? v : md;
            }
        }
        md = fmaxf(md, __shfl_xor(md, 1));
        md = fmaxf(md, __shfl_xor(md, 2));
        if (q == 0) {
            float m;
            if (md < -2.9e38f) m = -2.0e38f;              // empty-split flag
            else { float e = srcS[r] + md; m = e > 0.f ? e : LRALPHA * e; }
            mS[r] = m;
        }
    }
    *(short8*)&BH[0][sdst] = stH;
    *(short8*)&BL[0][sdst] = stL;
    stH = *(const short8*)(whH + gbase + 64);
    stL = *(const short8*)(whL + gbase + 64);
    __syncthreads();

    const int w = t >> 6, l = t & 63;
    const int rA = 16 * w + (l & 15);
    const int q8 = (l >> 4) * 8;
    const float src_r = srcS[rA];
    const float m_r   = mS[rA];
    const bool  empty = (m_r <= -1.9e38f);
    const unsigned int* browp = bits + (long)(i0 + rA) * 128 + js * (JS / 32);
    const short8 ONES = {(short)0x3F80, (short)0x3F80, (short)0x3F80, (short)0x3F80,
                         (short)0x3F80, (short)0x3F80, (short)0x3F80, (short)0x3F80};

    f32x4 acc[4] = {};
    f32x4 acc_d = {};

    for (int jt = 0; jt < JTILES; ++jt) {
        const int cur = jt & 1;
        if (jt + 1 < JTILES) {
            *(short8*)&BH[cur ^ 1][sdst] = stH;
            *(short8*)&BL[cur ^ 1][sdst] = stL;
        }
        if (jt + 2 < JTILES) {
            stH = *(const short8*)(whH + gbase + (jt + 2) * 64);
            stL = *(const short8*)(whL + gbase + (jt + 2) * 64);
        }
        // ---- P in A-fragment registers: lrelu+exp+mask, truncate-split pack ----
        unsigned int bw0 = browp[jt * 2], bw1 = browp[jt * 2 + 1];
        short8 aH0, aL0, aH1, aL1;
        #pragma unroll
        for (int kt = 0; kt < 2; ++kt) {
            unsigned int bw = kt ? bw1 : bw0;
            float4 d0 = *(const float4*)&dstS[jt * 64 + kt * 32 + q8];
            float4 d1 = *(const float4*)&dstS[jt * 64 + kt * 32 + q8 + 4];
            float dv[8] = {d0.x, d0.y, d0.z, d0.w, d1.x, d1.y, d1.z, d1.w};
            float pv[8];
            #pragma unroll
            for (int e = 0; e < 8; ++e) {
                float v = src_r + dv[e];
                v = fmaxf(v, LRALPHA * v);              // leakyrelu
                float pe = __expf(v - m_r);
                bool valid = (bw >> (q8 + e)) & 1u;
                pv[e] = empty ? 1.f : (valid ? pe : 0.f);
            }
            int4v hw, lw;
            #pragma unroll
            for (int pp = 0; pp < 4; ++pp) PACK_PAIR(pv[2*pp], pv[2*pp+1], hw[pp], lw[pp]);
            short8 aH = __builtin_bit_cast(short8, hw);
            short8 aL = __builtin_bit_cast(short8, lw);
            // denominator on the (idle) MFMA pipe: row-sums via B = ones
            acc_d = __builtin_amdgcn_mfma_f32_16x16x32_bf16(aH, ONES, acc_d, 0, 0, 0);
            acc_d = __builtin_amdgcn_mfma_f32_16x16x32_bf16(aL, ONES, acc_d, 0, 0, 0);
            if (kt == 0) { aH0 = aH; aL0 = aL; } else { aH1 = aH; aL1 = aL; }
        }
        // ---- bf16x3 MFMA: 4 col-tiles x 2 k-steps ----
        #pragma unroll
        for (int kt = 0; kt < 2; ++kt) {
            short8 aH = kt ? aH1 : aH0;
            short8 aL = kt ? aL1 : aL0;
            #pragma unroll
            for (int ct = 0; ct < 4; ++ct) {
                const int c = ct * 16 + (l & 15);
                const int off = c * 64 + ((((kt * 4) + (l >> 4)) ^ (c & 7)) << 3);
                short8 bh = *(const short8*)&BH[cur][off];
                short8 bl = *(const short8*)&BL[cur][off];
                acc[ct] = __builtin_amdgcn_mfma_f32_16x16x32_bf16(aH, bh, acc[ct], 0, 0, 0);
                acc[ct] = __builtin_amdgcn_mfma_f32_16x16x32_bf16(aH, bl, acc[ct], 0, 0, 0);
                acc[ct] = __builtin_amdgcn_mfma_f32_16x16x32_bf16(aL, bh, acc[ct], 0, 0, 0);
            }
        }
        __syncthreads();
    }

    // partial write: D layout col=l&15, row=(l>>4)*4+reg
    const int colb = y * 64 + (l & 15);
    #pragma unroll
    for (int ct = 0; ct < 4; ++ct) {
        #pragma unroll
        for (int g = 0; g < 4; ++g) {
            int row = 16 * w + (l >> 4) * 4 + g;
            partA[((long)js * NN + i0 + row) * OUTD + colb + ct * 16] = acc[ct][g];
        }
    }
    if ((l & 15) == 0) {
        long mdoff = ((long)js * NHEADS + y) * NN + i0 + 16 * w + (l >> 4) * 4;
        #pragma unroll
        for (int g = 0; g < 4; ++g) md_d[mdoff + g] = acc_d[g];
    }
    if (l < 16) {
        md_m[((long)js * NHEADS + y) * NN + i0 + 16 * w + l] = m_r;
    }
}

// ---------------- combine split partials + ELU -> bf16 hi/lo ----------------
__global__ __launch_bounds__(256) void combine_kernel(
    const float* __restrict__ partA, const float* __restrict__ md_m,
    const float* __restrict__ md_d, unsigned short* __restrict__ outH,
    unsigned short* __restrict__ outL)
{
    int idx4 = (blockIdx.x * 256 + threadIdx.x) * 4;
    int row  = idx4 >> 9;
    int col  = idx4 & 511;
    int slot = col >> 6;
    float m[NSPLIT], w[NSPLIT];
    float M = -3.4e38f;
    #pragma unroll
    for (int s = 0; s < NSPLIT; ++s) {
        m[s] = md_m[((long)s * NHEADS + slot) * NN + row];
        M = fmaxf(M, m[s]);
    }
    float den = 0.f;
    #pragma unroll
    for (int s = 0; s < NSPLIT; ++s) {
        w[s] = __expf(m[s] - M);
        den += w[s] * md_d[((long)s * NHEADS + slot) * NN + row];
    }
    float4 num = {0.f, 0.f, 0.f, 0.f};
    #pragma unroll
    for (int s = 0; s < NSPLIT; ++s) {
        float4 a = *(const float4*)&partA[((long)s * NN + row) * OUTD + col];
        num.x += w[s] * a.x; num.y += w[s] * a.y;
        num.z += w[s] * a.z; num.w += w[s] * a.w;
    }
    float inv = 1.f / den;
    float o[4]; const float* pn = &num.x;
    #pragma unroll
    for (int j = 0; j < 4; ++j) {
        float v = pn[j] * inv;
        o[j] = v > 0.f ? v : (__expf(v) - 1.f);   // ELU
    }
    int h0, h1, l0, l1;
    PACK_PAIR(o[0], o[1], h0, l0);
    PACK_PAIR(o[2], o[3], h1, l1);
    uint2v hv = {(unsigned)h0, (unsigned)h1};
    uint2v lv = {(unsigned)l0, (unsigned)l1};
    *(uint2v*)&outH[(long)row * OUTD + col] = hv;
    *(uint2v*)&outL[(long)row * OUTD + col] = lv;
}

extern "C" void kernel_launch(void* const* d_in, const int* in_sizes, int n_in,
                              void* d_out, int out_size, void* d_ws, size_t ws_size,
                              hipStream_t stream) {
    const float* x   = (const float*)d_in[0];
    const int*   adj = (const int*)d_in[1];
    const float* W1  = (const float*)d_in[2];
    const float* a1  = (const float*)d_in[3];
    const float* Wo  = (const float*)d_in[4];
    const float* ao  = (const float*)d_in[5];
    const float* l1w = (const float*)d_in[6];
    const float* l1b = (const float*)d_in[7];
    const float* l2w = (const float*)d_in[8];
    const float* l2b = (const float*)d_in[9];
    float* out = (float*)d_out;

    char* ws = (char*)d_ws;
    unsigned int* bits = (unsigned int*)(ws + OFF_BITS);
    float* WhA  = (float*)(ws + OFF_WHA);
    float* srcB = (float*)(ws + OFF_SRC);
    float* dstB = (float*)(ws + OFF_DST);
    float* mdm  = (float*)(ws + OFF_MDM);
    float* mdd  = (float*)(ws + OFF_MDD);
    unsigned short* xhH = (unsigned short*)(ws + OFF_XHH);
    unsigned short* xhL = (unsigned short*)(ws + OFF_XHL);
    unsigned short* whH = (unsigned short*)(ws + OFF_WHH);
    unsigned short* whL = (unsigned short*)(ws + OFF_WHL);
    float* part = (float*)(ws + OFF_PART);
    unsigned short* l1oH = (unsigned short*)(ws + OFF_L1OH);
    unsigned short* l1oL = (unsigned short*)(ws + OFF_L1OL);
    unsigned short* w1tH = (unsigned short*)(ws + OFF_W1TH);
    unsigned short* w1tL = (unsigned short*)(ws + OFF_W1TL);
    unsigned short* wotH = (unsigned short*)(ws + OFF_WOTH);
    unsigned short* wotL = (unsigned short*)(ws + OFF_WOTL);
    unsigned short* l1wH = (unsigned short*)(ws + OFF_L1WH);
    unsigned short* l1wL = (unsigned short*)(ws + OFF_L1WL);
    unsigned short* l2wH = (unsigned short*)(ws + OFF_L2WH);
    unsigned short* l2wL = (unsigned short*)(ws + OFF_L2WL);

    // 0) adjacency bitmask + operand splits
    pack_bits_kernel<<<65536, 256, 0, stream>>>(adj, bits);
    splitA_kernel<<<1024, 256, 0, stream>>>(x, xhH, xhL);                        // x
    splitBT_kernel<<<dim3(1, 8, 8), 256, 0, stream>>>(W1, w1tH, w1tL, NFEAT, NHID,
        (long)NFEAT * NHID, (long)NHID * NFEAT);                                 // W1^T per head
    splitBT_kernel<<<dim3(8, 8, 1), 256, 0, stream>>>(Wo, wotH, wotL, 512, OUTD, 0, 0);
    splitBT_kernel<<<dim3(16, 8, 1), 256, 0, stream>>>(l1w, l1wH, l1wL, OUTD, 1024, 0, 0);
    splitBT_kernel<<<dim3(8, 16, 1), 256, 0, stream>>>(l2w, l2wH, l2wL, 1024, OUTD, 0, 0);

    // 1) Wh1[h] = x @ W1[h]  (fp32 out for srcdst/whsplit)
    mgemm_kernel<1,0,0,0><<<dim3(32, 1, 8), 256, 0, stream>>>(
        xhH, xhL, w1tH, w1tL, WhA, nullptr, nullptr, nullptr,
        NHID, NFEAT, (long)NHID * NFEAT, (long)NN * NHID);
    // 2) src1/dst1
    srcdst_kernel<<<8192, 256, 0, stream>>>(WhA, a1, srcB, dstB, NHEADS*NN, NN, NHID);
    // 3) transpose+split Wh1 -> whH/whL [y][c][j]
    whsplit_kernel<<<dim3(64, 8), 256, 0, stream>>>(WhA, (long)NN*NHID, NHID, whH, whL);
    // 4) layer-1 attention partials
    attn_kernel<<<dim3(32, 8, NSPLIT), 512, 0, stream>>>(
        whH, whL, srcB, dstB, NN, bits, part, mdm, mdd);
    // 5) combine -> x1 bf16 hi/lo
    combine_kernel<<<2048, 256, 0, stream>>>(part, mdm, mdd, xhH, xhL);
    // 6) Wh2 = x1 @ Wo (fp32)
    mgemm_kernel<1,0,0,0><<<dim3(32, 8, 1), 256, 0, stream>>>(
        xhH, xhL, wotH, wotL, WhA, nullptr, nullptr, nullptr, OUTD, 512, 0, 0);
    // 7) src2/dst2
    srcdst_kernel<<<1024, 256, 0, stream>>>(WhA, ao, srcB, dstB, NN, NN, OUTD);
    // 8) transpose+split Wh2 (y = col-slice)
    whsplit_kernel<<<dim3(64, 8), 256, 0, stream>>>(WhA, 64L, OUTD, whH, whL);
    // 9) layer-2 attention partials
    attn_kernel<<<dim3(32, 8, NSPLIT), 512, 0, stream>>>(
        whH, whL, srcB, dstB, 0, bits, part, mdm, mdd);
    // 10) combine -> h2 bf16 hi/lo
    combine_kernel<<<2048, 256, 0, stream>>>(part, mdm, mdd, xhH, xhL);
    // 11) lin1 + bias + ReLU -> l1o bf16 hi/lo (overwrites part, now dead)
    mgemm_kernel<0,1,1,1><<<dim3(32, 16, 1), 256, 0, stream>>>(
        xhH, xhL, l1wH, l1wL, nullptr, l1oH, l1oL, l1b, 1024, OUTD, 0, 0);
    // 12) lin2 + bias -> out
    mgemm_kernel<1,0,1,0><<<dim3(32, 8, 1), 256, 0, stream>>>(
        l1oH, l1oL, l2wH, l2wL, out, nullptr, nullptr, l2b, OUTD, 1024, 0, 0);
}

// Round 6
// 431.567 us; speedup vs baseline: 2.5330x; 1.0718x over previous
//
#include <hip/hip_runtime.h>

#define NN 4096
#define NFEAT 512
#define NHID 64
#define NHEADS 8
#define OUTD 512
#define LRALPHA 0.2f
#define LOG2E 1.4426950408889634f

typedef __attribute__((ext_vector_type(4))) float f32x4;
typedef __attribute__((ext_vector_type(8))) short short8;
typedef __attribute__((ext_vector_type(4))) int   int4v;
typedef __attribute__((ext_vector_type(2))) unsigned uint2v;

// ---------------- workspace layout (bytes) ----------------
#define OFF_BITS (size_t)0x0        // 2 MB bitmask
#define OFF_XHH  (size_t)0x200000   // 4 MB bf16 hi: x, then x1, then h2 [4096][512]
#define OFF_XHL  (size_t)0x600000   // 4 MB lo
#define OFF_WHH  (size_t)0xA00000   // 4 MB attn-transposed Wh hi [y][c 64][j 4096]
#define OFF_WHL  (size_t)0xE00000   // 4 MB lo
#define OFF_W1TH (size_t)0x1200000  // [8][64][512] 512 KB
#define OFF_W1TL (size_t)0x1280000
#define OFF_WOTH (size_t)0x1300000  // [512][512] 512 KB
#define OFF_WOTL (size_t)0x1380000
#define OFF_L1WH (size_t)0x1400000  // [1024][512] 1 MB
#define OFF_L1WL (size_t)0x1500000
#define OFF_L2WH (size_t)0x1600000  // [512][1024] 1 MB
#define OFF_L2WL (size_t)0x1700000
#define OFF_SRC  (size_t)0x1800000  // 128 KB [8][4096] (layer1)
#define OFF_DST  (size_t)0x1820000  // 128 KB
#define OFF_SRC2 (size_t)0x1840000  // 16 KB [4096] (layer2, atomic)
#define OFF_DST2 (size_t)0x1844000  // 16 KB
#define OFF_MDM  (size_t)0x1850000  // 512 KB [<=4][8][4096]
#define OFF_MDD  (size_t)0x18D0000  // 512 KB
#define OFF_PART (size_t)0x1950000  // NSPLIT*8 MB partials; later l1o hi/lo (16 MB)
#define OFF_L1OH OFF_PART
#define OFF_L1OL (OFF_PART + (size_t)0x800000)
#define WS_NEED4 (OFF_PART + (size_t)0x2000000)   // 57.3 MB -> NSPLIT=4
#define WS_NEED2 (OFF_PART + (size_t)0x1000000)   // 43.3 MB -> NSPLIT=2 fallback

__device__ inline unsigned cvt_pk_bf16(float lo, float hi) {
    // dst.low16 = bf16(lo), dst.high16 = bf16(hi), RTNE
    unsigned r;
    asm("v_cvt_pk_bf16_f32 %0, %1, %2" : "=v"(r) : "v"(lo), "v"(hi));
    return r;
}
__device__ inline void pack_pair(float ve, float vo, unsigned& hw, unsigned& lw) {
    hw = cvt_pk_bf16(ve, vo);
    float he = __uint_as_float(hw << 16);
    float ho = __uint_as_float(hw & 0xFFFF0000u);
    lw = cvt_pk_bf16(ve - he, vo - ho);
}
__device__ inline float exp2_fast(float x) {
#if __has_builtin(__builtin_amdgcn_exp2f)
    return __builtin_amdgcn_exp2f(x);
#else
    float r; asm("v_exp_f32 %0, %1" : "=v"(r) : "v"(x)); return r;
#endif
}

// ---------------- pack adjacency into bitmask ----------------
__global__ __launch_bounds__(256) void pack_bits_kernel(
    const int* __restrict__ adj, unsigned int* __restrict__ bits)
{
    int wid  = (blockIdx.x * 256 + threadIdx.x) >> 6;
    int lane = threadIdx.x & 63;
    int row  = wid >> 6;
    int j0   = (wid & 63) << 6;
    int v    = adj[(long)row * NN + j0 + lane];
    unsigned long long m = __ballot(v > 0);
    if (lane == 0)  bits[row * 128 + (j0 >> 5)]     = (unsigned int)m;
    if (lane == 32) bits[row * 128 + (j0 >> 5) + 1] = (unsigned int)(m >> 32);
}

// ---------------- zero small buffers ----------------
__global__ __launch_bounds__(256) void zero_kernel(float* __restrict__ a,
                                                   float* __restrict__ b)
{
    int i = blockIdx.x * 256 + threadIdx.x;
    if (i < NN) { a[i] = 0.f; b[i] = 0.f; }
}

// ---------------- split fp32 stream -> bf16 hi/lo ----------------
__global__ __launch_bounds__(256) void splitA_kernel(
    const float* __restrict__ in, unsigned short* __restrict__ oh,
    unsigned short* __restrict__ ol)
{
    long i = ((long)blockIdx.x * 256 + threadIdx.x) * 8;
    float4 a = *(const float4*)&in[i], b = *(const float4*)&in[i + 4];
    float v[8] = {a.x, a.y, a.z, a.w, b.x, b.y, b.z, b.w};
    int4v hw, lw;
    #pragma unroll
    for (int pp = 0; pp < 4; ++pp) {
        unsigned h, l; pack_pair(v[2*pp], v[2*pp+1], h, l);
        hw[pp] = (int)h; lw[pp] = (int)l;
    }
    *(short8*)&oh[i] = __builtin_bit_cast(short8, hw);
    *(short8*)&ol[i] = __builtin_bit_cast(short8, lw);
}

// ---------------- transpose+split weights: fp32 [K][N] -> bf16 hi/lo [N][K] ----------------
__global__ __launch_bounds__(256) void splitBT_kernel(
    const float* __restrict__ B, unsigned short* __restrict__ oh,
    unsigned short* __restrict__ ol, int K, int N, long srcZ, long dstZ)
{
    __shared__ float tile[64][65];
    const int t = threadIdx.x;
    const int n0 = blockIdx.x * 64, k0 = blockIdx.y * 64;
    B  += srcZ * blockIdx.z;
    oh += dstZ * blockIdx.z;
    ol += dstZ * blockIdx.z;
    #pragma unroll
    for (int it = 0; it < 4; ++it) {
        int k = it * 16 + (t >> 4);
        *(float4*)&tile[k][(t & 15) * 4] =
            *(const float4*)&B[(long)(k0 + k) * N + n0 + (t & 15) * 4];
    }
    __syncthreads();
    const int n = t >> 2, kc = (t & 3) * 16;
    #pragma unroll
    for (int g = 0; g < 2; ++g) {
        int4v hw, lw;
        #pragma unroll
        for (int pp = 0; pp < 4; ++pp) {
            unsigned h, l;
            pack_pair(tile[kc + g*8 + 2*pp][n], tile[kc + g*8 + 2*pp + 1][n], h, l);
            hw[pp] = (int)h; lw[pp] = (int)l;
        }
        long ob = (long)(n0 + n) * K + k0 + kc + g * 8;
        *(short8*)&oh[ob] = __builtin_bit_cast(short8, hw);
        *(short8*)&ol[ob] = __builtin_bit_cast(short8, lw);
    }
}

// ---------------- bf16x3 MFMA GEMM with fused epilogues ----------------
// EPI: 0 = write C f32 (+bias/relu); 1 = write Ch/Cl bf16 split (+bias/relu)
//      2 = GAT layer-1: transposed whT store + direct src/dst dots (z = head)
//      3 = GAT layer-2: transposed whT store + atomic src/dst dots
template<int EPI, int DO_BIAS, int DO_RELU>
__global__ __launch_bounds__(256, 3) void mgemm_kernel(
    const unsigned short* __restrict__ Ah, const unsigned short* __restrict__ Al,
    const unsigned short* __restrict__ Bh, const unsigned short* __restrict__ Bl,
    float* __restrict__ C, unsigned short* __restrict__ Ch,
    unsigned short* __restrict__ Cl, const float* __restrict__ bias,
    const float* __restrict__ avec, float* __restrict__ srcO, float* __restrict__ dstO,
    unsigned short* __restrict__ tH, unsigned short* __restrict__ tL,
    int N, int K, long bZ, long cZ, int aoff)
{
    __shared__ unsigned short AH[2][4096], AL[2][4096];   // 128x32
    __shared__ unsigned short BHs[2][2048], BLs[2][2048]; // 64x32

    const int t = threadIdx.x;
    const int m0 = blockIdx.x * 128, n0 = blockIdx.y * 64;
    const int zi = blockIdx.z;
    Bh += bZ * zi; Bl += bZ * zi;

    const int ar0 = t >> 2, ar1 = 64 + (t >> 2), akb = t & 3;
    const unsigned short* pAh = Ah + (long)(m0 + ar0) * K + akb * 8;
    const unsigned short* pAl = Al + (long)(m0 + ar0) * K + akb * 8;
    const unsigned short* pBh = Bh + (long)(n0 + ar0) * K + akb * 8;
    const unsigned short* pBl = Bl + (long)(n0 + ar0) * K + akb * 8;
    const long aRow1 = (long)64 * K;
    const int adst0 = ar0 * 32 + ((akb ^ ((ar0 >> 1) & 3)) << 3);
    const int adst1 = ar1 * 32 + ((akb ^ ((ar1 >> 1) & 3)) << 3);

    short8 sh0, sh1, sl0, sl1, sbh, sbl;
    const int S = K / 32;

#define MG_LOAD(s) { long o = (long)(s) * 32;                     \
        sh0 = *(const short8*)(pAh + o);                          \
        sh1 = *(const short8*)(pAh + aRow1 + o);                  \
        sl0 = *(const short8*)(pAl + o);                          \
        sl1 = *(const short8*)(pAl + aRow1 + o);                  \
        sbh = *(const short8*)(pBh + o);                          \
        sbl = *(const short8*)(pBl + o); }
#define MG_COMMIT(b) {                                            \
        *(short8*)&AH[b][adst0] = sh0; *(short8*)&AH[b][adst1] = sh1; \
        *(short8*)&AL[b][adst0] = sl0; *(short8*)&AL[b][adst1] = sl1; \
        *(short8*)&BHs[b][adst0] = sbh; *(short8*)&BLs[b][adst0] = sbl; }

    MG_LOAD(0);
    MG_COMMIT(0);
    if (S > 1) MG_LOAD(1);
    __syncthreads();

    const int w = t >> 6, l = t & 63;
    const int kb = l >> 4;
    const int r0 = w * 32 + (l & 15), r1 = r0 + 16;
    const int ao0 = r0 * 32 + ((kb ^ ((r0 >> 1) & 3)) << 3);
    const int ao1 = r1 * 32 + ((kb ^ ((r1 >> 1) & 3)) << 3);

    f32x4 acc0[4] = {}, acc1[4] = {};

    for (int s = 0; s < S; ++s) {
        const int cur = s & 1;
        if (s + 1 < S) MG_COMMIT(cur ^ 1);
        if (s + 2 < S) MG_LOAD(s + 2);

        short8 a0h = *(const short8*)&AH[cur][ao0];
        short8 a0l = *(const short8*)&AL[cur][ao0];
        short8 a1h = *(const short8*)&AH[cur][ao1];
        short8 a1l = *(const short8*)&AL[cur][ao1];
        #pragma unroll
        for (int ct = 0; ct < 4; ++ct) {
            const int n = ct * 16 + (l & 15);
            const int bo = n * 32 + ((kb ^ ((n >> 1) & 3)) << 3);
            short8 bh = *(const short8*)&BHs[cur][bo];
            short8 bl = *(const short8*)&BLs[cur][bo];
            acc0[ct] = __builtin_amdgcn_mfma_f32_16x16x32_bf16(a0h, bh, acc0[ct], 0, 0, 0);
            acc0[ct] = __builtin_amdgcn_mfma_f32_16x16x32_bf16(a0h, bl, acc0[ct], 0, 0, 0);
            acc0[ct] = __builtin_amdgcn_mfma_f32_16x16x32_bf16(a0l, bh, acc0[ct], 0, 0, 0);
            acc1[ct] = __builtin_amdgcn_mfma_f32_16x16x32_bf16(a1h, bh, acc1[ct], 0, 0, 0);
            acc1[ct] = __builtin_amdgcn_mfma_f32_16x16x32_bf16(a1h, bl, acc1[ct], 0, 0, 0);
            acc1[ct] = __builtin_amdgcn_mfma_f32_16x16x32_bf16(a1l, bh, acc1[ct], 0, 0, 0);
        }
        __syncthreads();
    }
#undef MG_LOAD
#undef MG_COMMIT

    if constexpr (EPI <= 1) {
        #pragma unroll
        for (int rs = 0; rs < 2; ++rs) {
            #pragma unroll
            for (int ct = 0; ct < 4; ++ct) {
                const int col = n0 + ct * 16 + (l & 15);
                float b = DO_BIAS ? bias[col] : 0.f;
                f32x4 av = rs ? acc1[ct] : acc0[ct];
                #pragma unroll
                for (int g = 0; g < 4; ++g) {
                    int row = m0 + w * 32 + rs * 16 + (l >> 4) * 4 + g;
                    float v = av[g] + b;
                    if (DO_RELU) v = v > 0.f ? v : 0.f;
                    if (EPI == 0) C[cZ * zi + (long)row * N + col] = v;
                    else {
                        unsigned u = __float_as_uint(v);
                        Ch[(long)row * N + col] = (unsigned short)((u + 0x7FFFu + ((u >> 16) & 1u)) >> 16);
                        unsigned hh = (u + 0x7FFFu + ((u >> 16) & 1u)) & 0xFFFF0000u;
                        // recompute hi float from rounded bf16 for residual
                        float hf = __uint_as_float(((u + 0x7FFFu + ((u >> 16) & 1u)) >> 16) << 16);
                        float lo = v - hf;
                        unsigned ul = __float_as_uint(lo);
                        Cl[(long)row * N + col] = (unsigned short)((ul + 0x7FFFu + ((ul >> 16) & 1u)) >> 16);
                        (void)hh;
                    }
                }
            }
        }
    } else {
        // ---- GAT epilogue: transposed bf16 hi/lo store + src/dst dots ----
        float avs[4], avd[4];
        #pragma unroll
        for (int ct = 0; ct < 4; ++ct) {
            int col = n0 + ct * 16 + (l & 15);
            avs[ct] = avec[(EPI == 2 ? zi * 2 * 64 : 0) + col];
            avd[ct] = avec[(EPI == 2 ? zi * 2 * 64 : 0) + aoff + col];
        }
        #pragma unroll
        for (int rs = 0; rs < 2; ++rs) {
            const int rbase = m0 + w * 32 + rs * 16 + (l >> 4) * 4;
            // transposed store: whT[y][c][j]
            #pragma unroll
            for (int ct = 0; ct < 4; ++ct) {
                const int col = n0 + ct * 16 + (l & 15);
                f32x4 av = rs ? acc1[ct] : acc0[ct];
                unsigned h0, l0, h1, l1;
                pack_pair(av[0], av[1], h0, l0);
                pack_pair(av[2], av[3], h1, l1);
                long tb = (EPI == 2 ? (long)zi * 262144 + (long)col * 4096
                                    : (long)(col >> 6) * 262144 + (long)(col & 63) * 4096)
                          + rbase;
                uint2v hv = {h0, h1}, lv = {l0, l1};
                *(uint2v*)&tH[tb] = hv;
                *(uint2v*)&tL[tb] = lv;
            }
            // src/dst dots (scaled by log2e for exp2 softmax downstream)
            #pragma unroll
            for (int g = 0; g < 4; ++g) {
                float sd = 0.f, dd = 0.f;
                #pragma unroll
                for (int ct = 0; ct < 4; ++ct) {
                    f32x4 av = rs ? acc1[ct] : acc0[ct];
                    sd += av[g] * avs[ct];
                    dd += av[g] * avd[ct];
                }
                #pragma unroll
                for (int off = 1; off < 16; off <<= 1) {
                    sd += __shfl_xor(sd, off);
                    dd += __shfl_xor(dd, off);
                }
                if ((l & 15) == 0) {
                    int row = rbase + g;
                    if (EPI == 2) {
                        srcO[zi * NN + row] = sd * LOG2E;
                        dstO[zi * NN + row] = dd * LOG2E;
                    } else {
                        atomicAdd(&srcO[row], sd * LOG2E);
                        atomicAdd(&dstO[row], dd * LOG2E);
                    }
                }
            }
        }
    }
}

// ---------------- MFMA split-j attention partials (exp2 domain) ----------------
template<int JS_>
__global__ __launch_bounds__(512, 4) void attn_kernel(
    const unsigned short* __restrict__ whH, const unsigned short* __restrict__ whL,
    const float* __restrict__ src, const float* __restrict__ dst, int snOff_y,
    const unsigned int* __restrict__ bits,
    float* __restrict__ partA, float* __restrict__ md_m, float* __restrict__ md_d)
{
    constexpr int JT_ = JS_ / 64;
    __shared__ unsigned short BH[2][4096];   // 64c x 64j bf16-hi, swizzled
    __shared__ unsigned short BL[2][4096];
    __shared__ float dstS[JS_];
    __shared__ float srcS[128], mS[128];

    const int t  = threadIdx.x;
    const int i0 = blockIdx.x * 128;
    const int y  = blockIdx.y;
    const int js = blockIdx.z;
    src += (long)snOff_y * y;
    dst += (long)snOff_y * y;

    const int sc = t >> 3, sb = t & 7;
    const long gbase = (long)y * 262144 + (long)sc * 4096 + (long)js * JS_ + sb * 8;
    const int sdst = sc * 64 + ((sb ^ (sc & 7)) << 3);

    short8 stH = *(const short8*)(whH + gbase);
    short8 stL = *(const short8*)(whL + gbase);

    if (t * 4 < JS_)
        *(float4*)&dstS[t * 4] = *(const float4*)&dst[(long)js * JS_ + t * 4];
    if (t < 128) srcS[t] = src[i0 + t];
    __syncthreads();

    // ---- pre-pass: exact local max of dst over valid j (4 thr/row) ----
    {
        constexpr int WPQ = JS_ / 128;
        const int r = t >> 2, q = t & 3;
        float md = -3.0e38f;
        const unsigned int* brow = bits + (long)(i0 + r) * 128 + js * (JS_ / 32) + q * WPQ;
        for (int wi = 0; wi < WPQ; ++wi) {
            unsigned int b = brow[wi];
            if (!b) continue;
            int base = q * (JS_ / 4) + wi * 32;
            while (b) {
                int bi = __ffs(b) - 1; b &= b - 1;
                float v = dstS[base + bi];
                md = v > md ? v : md;
            }
        }
        md = fmaxf(md, __shfl_xor(md, 1));
        md = fmaxf(md, __shfl_xor(md, 2));
        if (q == 0) {
            float m;
            if (md < -2.9e38f) m = -2.0e38f;              // empty-split flag
            else { float e = srcS[r] + md; m = fmaxf(e, LRALPHA * e); }
            mS[r] = m;
        }
    }
    *(short8*)&BH[0][sdst] = stH;
    *(short8*)&BL[0][sdst] = stL;
    stH = *(const short8*)(whH + gbase + 64);
    stL = *(const short8*)(whL + gbase + 64);
    __syncthreads();

    const int w = t >> 6, l = t & 63;
    const int rA = 16 * w + (l & 15);
    const int q8 = (l >> 4) * 8;
    const float src_r = srcS[rA];
    const float m_r   = mS[rA];
    const bool  empty = (m_r <= -1.9e38f);
    const unsigned int* browp = bits + (long)(i0 + rA) * 128 + js * (JS_ / 32);
    const short8 ONES = {(short)0x3F80, (short)0x3F80, (short)0x3F80, (short)0x3F80,
                         (short)0x3F80, (short)0x3F80, (short)0x3F80, (short)0x3F80};

    f32x4 acc[4] = {};
    f32x4 acc_d = {};

    for (int jt = 0; jt < JT_; ++jt) {
        const int cur = jt & 1;
        if (jt + 1 < JT_) {
            *(short8*)&BH[cur ^ 1][sdst] = stH;
            *(short8*)&BL[cur ^ 1][sdst] = stL;
        }
        if (jt + 2 < JT_) {
            stH = *(const short8*)(whH + gbase + (jt + 2) * 64);
            stL = *(const short8*)(whL + gbase + (jt + 2) * 64);
        }
        // ---- P in A-fragments: lrelu + exp2 + mask, RTNE hi/lo pack ----
        unsigned int bw0 = browp[jt * 2], bw1 = browp[jt * 2 + 1];
        short8 aH0, aL0, aH1, aL1;
        #pragma unroll
        for (int kt = 0; kt < 2; ++kt) {
            unsigned int bw = kt ? bw1 : bw0;
            float4 d0 = *(const float4*)&dstS[jt * 64 + kt * 32 + q8];
            float4 d1 = *(const float4*)&dstS[jt * 64 + kt * 32 + q8 + 4];
            float dv[8] = {d0.x, d0.y, d0.z, d0.w, d1.x, d1.y, d1.z, d1.w};
            float pv[8];
            #pragma unroll
            for (int e = 0; e < 8; ++e) {
                float v = src_r + dv[e];
                v = fmaxf(v, LRALPHA * v);
                float s = v - m_r;
                bool valid = (bw >> (q8 + e)) & 1u;
                s = valid ? s : -1.0e30f;
                s = empty ? 0.f : s;
                pv[e] = exp2_fast(s);
            }
            int4v hw, lw;
            #pragma unroll
            for (int pp = 0; pp < 4; ++pp) {
                unsigned h, lo; pack_pair(pv[2*pp], pv[2*pp+1], h, lo);
                hw[pp] = (int)h; lw[pp] = (int)lo;
            }
            short8 aH = __builtin_bit_cast(short8, hw);
            short8 aL = __builtin_bit_cast(short8, lw);
            acc_d = __builtin_amdgcn_mfma_f32_16x16x32_bf16(aH, ONES, acc_d, 0, 0, 0);
            acc_d = __builtin_amdgcn_mfma_f32_16x16x32_bf16(aL, ONES, acc_d, 0, 0, 0);
            if (kt == 0) { aH0 = aH; aL0 = aL; } else { aH1 = aH; aL1 = aL; }
        }
        // ---- bf16x3 MFMA: 4 col-tiles x 2 k-steps ----
        #pragma unroll
        for (int kt = 0; kt < 2; ++kt) {
            short8 aH = kt ? aH1 : aH0;
            short8 aL = kt ? aL1 : aL0;
            #pragma unroll
            for (int ct = 0; ct < 4; ++ct) {
                const int c = ct * 16 + (l & 15);
                const int off = c * 64 + ((((kt * 4) + (l >> 4)) ^ (c & 7)) << 3);
                short8 bh = *(const short8*)&BH[cur][off];
                short8 bl = *(const short8*)&BL[cur][off];
                acc[ct] = __builtin_amdgcn_mfma_f32_16x16x32_bf16(aH, bh, acc[ct], 0, 0, 0);
                acc[ct] = __builtin_amdgcn_mfma_f32_16x16x32_bf16(aH, bl, acc[ct], 0, 0, 0);
                acc[ct] = __builtin_amdgcn_mfma_f32_16x16x32_bf16(aL, bh, acc[ct], 0, 0, 0);
            }
        }
        __syncthreads();
    }

    const int colb = y * 64 + (l & 15);
    #pragma unroll
    for (int ct = 0; ct < 4; ++ct) {
        #pragma unroll
        for (int g = 0; g < 4; ++g) {
            int row = 16 * w + (l >> 4) * 4 + g;
            partA[((long)js * NN + i0 + row) * OUTD + colb + ct * 16] = acc[ct][g];
        }
    }
    if ((l & 15) == 0) {
        long mdoff = ((long)js * NHEADS + y) * NN + i0 + 16 * w + (l >> 4) * 4;
        #pragma unroll
        for (int g = 0; g < 4; ++g) md_d[mdoff + g] = acc_d[g];
    }
    if (l < 16) {
        md_m[((long)js * NHEADS + y) * NN + i0 + 16 * w + l] = m_r;
    }
}

// ---------------- combine split partials + ELU -> bf16 hi/lo ----------------
template<int NS>
__global__ __launch_bounds__(256) void combine_kernel(
    const float* __restrict__ partA, const float* __restrict__ md_m,
    const float* __restrict__ md_d, unsigned short* __restrict__ outH,
    unsigned short* __restrict__ outL)
{
    int idx4 = (blockIdx.x * 256 + threadIdx.x) * 4;
    int row  = idx4 >> 9;
    int col  = idx4 & 511;
    int slot = col >> 6;
    float m[NS], w[NS];
    float M = -3.4e38f;
    #pragma unroll
    for (int s = 0; s < NS; ++s) {
        m[s] = md_m[((long)s * NHEADS + slot) * NN + row];
        M = fmaxf(M, m[s]);
    }
    float den = 0.f;
    #pragma unroll
    for (int s = 0; s < NS; ++s) {
        w[s] = exp2_fast(m[s] - M);
        den += w[s] * md_d[((long)s * NHEADS + slot) * NN + row];
    }
    float4 num = {0.f, 0.f, 0.f, 0.f};
    #pragma unroll
    for (int s = 0; s < NS; ++s) {
        float4 a = *(const float4*)&partA[((long)s * NN + row) * OUTD + col];
        num.x += w[s] * a.x; num.y += w[s] * a.y;
        num.z += w[s] * a.z; num.w += w[s] * a.w;
    }
    float inv = 1.f / den;
    float o[4]; const float* pn = &num.x;
    #pragma unroll
    for (int j = 0; j < 4; ++j) {
        float v = pn[j] * inv;
        o[j] = v > 0.f ? v : (__expf(v) - 1.f);   // ELU (natural e)
    }
    unsigned h0, l0, h1, l1;
    pack_pair(o[0], o[1], h0, l0);
    pack_pair(o[2], o[3], h1, l1);
    uint2v hv = {h0, h1}, lv = {l0, l1};
    *(uint2v*)&outH[(long)row * OUTD + col] = hv;
    *(uint2v*)&outL[(long)row * OUTD + col] = lv;
}

extern "C" void kernel_launch(void* const* d_in, const int* in_sizes, int n_in,
                              void* d_out, int out_size, void* d_ws, size_t ws_size,
                              hipStream_t stream) {
    const float* x   = (const float*)d_in[0];
    const int*   adj = (const int*)d_in[1];
    const float* W1  = (const float*)d_in[2];
    const float* a1  = (const float*)d_in[3];
    const float* Wo  = (const float*)d_in[4];
    const float* ao  = (const float*)d_in[5];
    const float* l1w = (const float*)d_in[6];
    const float* l1b = (const float*)d_in[7];
    const float* l2w = (const float*)d_in[8];
    const float* l2b = (const float*)d_in[9];
    float* out = (float*)d_out;

    char* ws = (char*)d_ws;
    unsigned int* bits = (unsigned int*)(ws + OFF_BITS);
    unsigned short* xhH = (unsigned short*)(ws + OFF_XHH);
    unsigned short* xhL = (unsigned short*)(ws + OFF_XHL);
    unsigned short* whH = (unsigned short*)(ws + OFF_WHH);
    unsigned short* whL = (unsigned short*)(ws + OFF_WHL);
    unsigned short* w1tH = (unsigned short*)(ws + OFF_W1TH);
    unsigned short* w1tL = (unsigned short*)(ws + OFF_W1TL);
    unsigned short* wotH = (unsigned short*)(ws + OFF_WOTH);
    unsigned short* wotL = (unsigned short*)(ws + OFF_WOTL);
    unsigned short* l1wH = (unsigned short*)(ws + OFF_L1WH);
    unsigned short* l1wL = (unsigned short*)(ws + OFF_L1WL);
    unsigned short* l2wH = (unsigned short*)(ws + OFF_L2WH);
    unsigned short* l2wL = (unsigned short*)(ws + OFF_L2WL);
    float* srcB = (float*)(ws + OFF_SRC);
    float* dstB = (float*)(ws + OFF_DST);
    float* src2 = (float*)(ws + OFF_SRC2);
    float* dst2 = (float*)(ws + OFF_DST2);
    float* mdm  = (float*)(ws + OFF_MDM);
    float* mdd  = (float*)(ws + OFF_MDD);
    float* part = (float*)(ws + OFF_PART);
    unsigned short* l1oH = (unsigned short*)(ws + OFF_L1OH);
    unsigned short* l1oL = (unsigned short*)(ws + OFF_L1OL);

    const int nsplit = (ws_size >= WS_NEED4) ? 4 : 2;

    // 0) prep: bitmask, zero layer-2 src/dst, operand splits
    pack_bits_kernel<<<65536, 256, 0, stream>>>(adj, bits);
    zero_kernel<<<16, 256, 0, stream>>>(src2, dst2);
    splitA_kernel<<<1024, 256, 0, stream>>>(x, xhH, xhL);
    splitBT_kernel<<<dim3(1, 8, 8), 256, 0, stream>>>(W1, w1tH, w1tL, NFEAT, NHID,
        (long)NFEAT * NHID, (long)NHID * NFEAT);
    splitBT_kernel<<<dim3(8, 8, 1), 256, 0, stream>>>(Wo, wotH, wotL, 512, OUTD, 0, 0);
    splitBT_kernel<<<dim3(16, 8, 1), 256, 0, stream>>>(l1w, l1wH, l1wL, OUTD, 1024, 0, 0);
    splitBT_kernel<<<dim3(8, 16, 1), 256, 0, stream>>>(l2w, l2wH, l2wL, 1024, OUTD, 0, 0);

    // 1) Wh1 = x@W1[h]: fused transposed-split store + src1/dst1 dots
    mgemm_kernel<2,0,0><<<dim3(32, 1, 8), 256, 0, stream>>>(
        xhH, xhL, w1tH, w1tL, nullptr, nullptr, nullptr, nullptr,
        a1, srcB, dstB, whH, whL, NHID, NFEAT, (long)NHID * NFEAT, 0, 64);
    // 2) layer-1 attention partials + combine -> x1
    if (nsplit == 4) {
        attn_kernel<1024><<<dim3(32, 8, 4), 512, 0, stream>>>(
            whH, whL, srcB, dstB, NN, bits, part, mdm, mdd);
        combine_kernel<4><<<2048, 256, 0, stream>>>(part, mdm, mdd, xhH, xhL);
    } else {
        attn_kernel<2048><<<dim3(32, 8, 2), 512, 0, stream>>>(
            whH, whL, srcB, dstB, NN, bits, part, mdm, mdd);
        combine_kernel<2><<<2048, 256, 0, stream>>>(part, mdm, mdd, xhH, xhL);
    }
    // 3) Wh2 = x1@Wo: fused transposed-split store + atomic src2/dst2 dots
    mgemm_kernel<3,0,0><<<dim3(32, 8, 1), 256, 0, stream>>>(
        xhH, xhL, wotH, wotL, nullptr, nullptr, nullptr, nullptr,
        ao, src2, dst2, whH, whL, OUTD, 512, 0, 0, 512);
    // 4) layer-2 attention partials + combine -> h2
    if (nsplit == 4) {
        attn_kernel<1024><<<dim3(32, 8, 4), 512, 0, stream>>>(
            whH, whL, src2, dst2, 0, bits, part, mdm, mdd);
        combine_kernel<4><<<2048, 256, 0, stream>>>(part, mdm, mdd, xhH, xhL);
    } else {
        attn_kernel<2048><<<dim3(32, 8, 2), 512, 0, stream>>>(
            whH, whL, src2, dst2, 0, bits, part, mdm, mdd);
        combine_kernel<2><<<2048, 256, 0, stream>>>(part, mdm, mdd, xhH, xhL);
    }
    // 5) lin1 + bias + ReLU -> l1o bf16 hi/lo (partials now dead)
    mgemm_kernel<1,1,1><<<dim3(32, 16, 1), 256, 0, stream>>>(
        xhH, xhL, l1wH, l1wL, nullptr, l1oH, l1oL, l1b,
        nullptr, nullptr, nullptr, nullptr, nullptr, 1024, OUTD, 0, 0, 0);
    // 6) lin2 + bias -> out
    mgemm_kernel<0,1,0><<<dim3(32, 8, 1), 256, 0, stream>>>(
        l1oH, l1oL, l2wH, l2wL, out, nullptr, nullptr, l2b,
        nullptr, nullptr, nullptr, nullptr, nullptr, OUTD, 1024, 0, 0, 0);
}